// Round 1
// baseline (3300.114 us; speedup 1.0000x reference)
//
#include <hip/hip_runtime.h>
#include <cstdint>
#include <cstddef>

#define NH   16
#define HD   64
#define RLEN 2048
#define BSZ  2
#define SLEN 64
#define NZ   64
#define ED   1024
#define KTOT 2112   // SLEN + RLEN

// ------------------------------------------------------------------
// GEMM: C[m][n] = sum_k A[m][k]*W[k][n] + bias[n], then *scale.
// mode 0: out[m*N+n]
// mode 1: head layout out[((b*NH+h)*Rr + r)*HD + d], m=r*Bsz+b, n=h*HD+d
// 128x128 tile, 256 threads, 8x8 per thread, K-step 16.
// ------------------------------------------------------------------
__global__ __launch_bounds__(256) void gemm128(
    const float* __restrict__ A, const float* __restrict__ W,
    const float* __restrict__ bias, float* __restrict__ out,
    int M, int K, int N, float scale, int mode, int Bsz, int Rr)
{
    __shared__ float As[128][17];
    __shared__ float Bs[16][129];
    const int t  = threadIdx.x;
    const int tx = t & 15, ty = t >> 4;
    const int m0 = blockIdx.y * 128, n0 = blockIdx.x * 128;

    float acc[8][8];
#pragma unroll
    for (int i = 0; i < 8; i++)
#pragma unroll
        for (int j = 0; j < 8; j++) acc[i][j] = 0.f;

    for (int k0 = 0; k0 < K; k0 += 16) {
#pragma unroll
        for (int i = 0; i < 8; i++) {
            int row = ty + i * 16;
            int m = m0 + row;
            As[row][tx] = (m < M) ? A[(size_t)m * K + k0 + tx] : 0.f;
        }
#pragma unroll
        for (int i = 0; i < 8; i++) {
            int row = (t >> 7) + i * 2, col = t & 127;
            Bs[row][col] = W[(size_t)(k0 + row) * N + n0 + col];
        }
        __syncthreads();
#pragma unroll
        for (int kk = 0; kk < 16; kk++) {
            float a[8], b[8];
#pragma unroll
            for (int i = 0; i < 8; i++) a[i] = As[ty + i * 16][kk];
#pragma unroll
            for (int j = 0; j < 8; j++) b[j] = Bs[kk][tx + j * 16];
#pragma unroll
            for (int i = 0; i < 8; i++)
#pragma unroll
                for (int j = 0; j < 8; j++) acc[i][j] += a[i] * b[j];
        }
        __syncthreads();
    }

#pragma unroll
    for (int i = 0; i < 8; i++) {
        int m = m0 + ty + i * 16;
        if (m >= M) continue;
        int r = m / Bsz, bb = m % Bsz;
#pragma unroll
        for (int j = 0; j < 8; j++) {
            int n = n0 + tx + j * 16;
            float c = (acc[i][j] + bias[n]) * scale;
            if (mode == 0) {
                out[(size_t)m * N + n] = c;
            } else {
                int h = n >> 6, d = n & 63;
                out[(((size_t)bb * NH + h) * Rr + r) * HD + d] = c;
            }
        }
    }
}

// ------------------------------------------------------------------
// In-place LayerNorm over trailing dim 64, one wave per row.
// x in head layout, rows = B*NH*R.
// ------------------------------------------------------------------
__global__ __launch_bounds__(256) void ln_heads(
    float* __restrict__ x, const float* __restrict__ g, const float* __restrict__ b)
{
    int row  = blockIdx.x * 4 + (threadIdx.x >> 6);
    int lane = threadIdx.x & 63;
    float v = x[(size_t)row * HD + lane];
    float s1 = v, s2 = v * v;
#pragma unroll
    for (int o = 32; o > 0; o >>= 1) {
        s1 += __shfl_xor(s1, o);
        s2 += __shfl_xor(s2, o);
    }
    float mean = s1 * (1.f / 64.f);
    float var  = s2 * (1.f / 64.f) - mean * mean;
    float y = (v - mean) * rsqrtf(var + 1e-5f) * g[lane] + b[lane];
    x[(size_t)row * HD + lane] = y;
}

// ------------------------------------------------------------------
// sum_q gather: sum_q[b][h][s][d] = emb_sum[ids[b][s]][h*64+d] * SCALE
// ------------------------------------------------------------------
__global__ __launch_bounds__(256) void sumq_gather(
    const float* __restrict__ emb, const int* __restrict__ ids,
    float* __restrict__ sum_q)
{
    int sb = blockIdx.x;            // 0..127
    int s = sb >> 1, b = sb & 1;
    int id = ids[b * SLEN + s];
    const float* src = emb + (size_t)id * ED;
    for (int e = threadIdx.x; e < ED; e += 256) {
        int h = e >> 6, d = e & 63;
        sum_q[(((size_t)b * NH + h) * SLEN + s) * HD + d] = src[e] * 0.125f;
    }
}

// ------------------------------------------------------------------
// Summary attention: one block per (b,h,s).
// scores[k] = dot(sum_q, reg_k[k]) + qr[rel_idx[b][s][k]], softmax over 2048,
// sum_x2[b][h][s][d] = sum_k w[k]*reg_v[k][d]
// ------------------------------------------------------------------
__global__ __launch_bounds__(256) void sum_attn(
    const float* __restrict__ sum_q, const float* __restrict__ K,
    const float* __restrict__ V, const float* __restrict__ r0,
    const int* __restrict__ rel_idx, float* __restrict__ sum_x2)
{
    const int bid = blockIdx.x;
    const int s = bid & 63, h = (bid >> 6) & 15, b = bid >> 10;
    const int t = threadIdx.x;

    __shared__ __align__(16) float qs[64];
    __shared__ float qr[64];
    __shared__ float sc[2048];
    __shared__ float red[256];

    const size_t bh = (size_t)b * NH + h;
    const float* qrow = sum_q + (bh * SLEN + s) * HD;
    if (t < 64) qs[t] = qrow[t];
    __syncthreads();

    if (t < 64) {
        const float* rz = r0 + ((size_t)h * NZ + t) * HD;
        float a = 0.f;
#pragma unroll
        for (int d = 0; d < 64; d++) a += qs[d] * rz[d];
        qr[t] = a;
    }
    __syncthreads();

    const float* Kb = K + bh * RLEN * HD;
    const int* ridx = rel_idx + ((size_t)b * KTOT + s) * RLEN;
    const float4* q4 = (const float4*)qs;
    float lmax = -1e30f;
    for (int kk = t; kk < RLEN; kk += 256) {
        const float4* kr = (const float4*)(Kb + (size_t)kk * HD);
        float a = 0.f;
#pragma unroll
        for (int d4 = 0; d4 < 16; d4++) {
            float4 kv = kr[d4], qv = q4[d4];
            a += kv.x * qv.x + kv.y * qv.y + kv.z * qv.z + kv.w * qv.w;
        }
        a += qr[ridx[kk]];
        sc[kk] = a;
        lmax = fmaxf(lmax, a);
    }
    red[t] = lmax;
    __syncthreads();
    for (int o = 128; o > 0; o >>= 1) {
        if (t < o) red[t] = fmaxf(red[t], red[t + o]);
        __syncthreads();
    }
    float m = red[0];
    __syncthreads();

    float lsum = 0.f;
    for (int kk = t; kk < RLEN; kk += 256) {
        float e = __expf(sc[kk] - m);
        sc[kk] = e;
        lsum += e;
    }
    red[t] = lsum;
    __syncthreads();
    for (int o = 128; o > 0; o >>= 1) {
        if (t < o) red[t] += red[t + o];
        __syncthreads();
    }
    float linv = 1.0f / red[0];
    __syncthreads();

    const float* Vb = V + bh * RLEN * HD;
    int d = t & 63, c = t >> 6;
    float acc = 0.f;
    for (int kk = c * 512; kk < (c + 1) * 512; kk++)
        acc += sc[kk] * Vb[(size_t)kk * HD + d];
    red[t] = acc;
    __syncthreads();
    if (t < 64) {
        float o = (red[t] + red[t + 64] + red[t + 128] + red[t + 192]) * linv;
        sum_x2[(bh * SLEN + s) * HD + t] = o;
    }
}

// ------------------------------------------------------------------
// sum_k2 / sum_v2: per row (b,h,s): y = LN(x @ W + bias). One wave per row.
// ------------------------------------------------------------------
__global__ __launch_bounds__(64) void k2v2(
    const float* __restrict__ sum_x2,
    const float* __restrict__ Wk2, const float* __restrict__ bk2,
    const float* __restrict__ Wv2, const float* __restrict__ bv2,
    const float* __restrict__ gk, const float* __restrict__ bk,
    const float* __restrict__ gv, const float* __restrict__ bv,
    float* __restrict__ sum_k2, float* __restrict__ sum_v2)
{
    int row = blockIdx.x;
    int d = threadIdx.x;
    __shared__ float xs[64];
    xs[d] = sum_x2[(size_t)row * HD + d];
    __syncthreads();

#pragma unroll
    for (int which = 0; which < 2; which++) {
        const float* W  = which ? Wv2 : Wk2;
        const float* bi = which ? bv2 : bk2;
        const float* g  = which ? gv : gk;
        const float* bb = which ? bv : bk;
        float* out      = which ? sum_v2 : sum_k2;
        float a = bi[d];
#pragma unroll
        for (int j = 0; j < 64; j++) a += xs[j] * W[j * HD + d];
        float s1 = a, s2 = a * a;
#pragma unroll
        for (int o = 32; o > 0; o >>= 1) {
            s1 += __shfl_xor(s1, o);
            s2 += __shfl_xor(s2, o);
        }
        float mean = s1 * (1.f / 64.f);
        float var  = s2 * (1.f / 64.f) - mean * mean;
        out[(size_t)row * HD + d] = (a - mean) * rsqrtf(var + 1e-5f) * g[d] + bb[d];
    }
}

// ------------------------------------------------------------------
// Main attention, flash-style. Block = (b, h, 32-row q-tile), 256 threads.
// 33 key tiles of 64: tile 0 = summary keys (sum_k2/sum_v2, no rel bias),
// tiles 1..32 = reg keys (reg_k/reg_v, + qr[rel_idx] bias).
// ------------------------------------------------------------------
__global__ __launch_bounds__(256) void reg_attn(
    const float* __restrict__ Q, const float* __restrict__ K,
    const float* __restrict__ V, const float* __restrict__ K2,
    const float* __restrict__ V2, const float* __restrict__ r0,
    const int* __restrict__ rel_idx, float* __restrict__ attn_out)
{
    const int bid = blockIdx.x;
    const int qt = bid & 63;
    const int h  = (bid >> 6) & 15;
    const int b  = bid >> 10;
    const int q0 = qt * 32;
    const int t  = threadIdx.x;

    __shared__ float Qs[32][65];
    __shared__ float qrs[32][64];
    __shared__ float Ks[64][65];
    __shared__ __align__(16) float Vs[64][64];
    __shared__ float St[32][65];
    __shared__ float mrow[32], lrow[32];

    const size_t bh = (size_t)b * NH + h;
    const float* Qbh  = Q  + bh * RLEN * HD;
    const float* Kbh  = K  + bh * RLEN * HD;
    const float* Vbh  = V  + bh * RLEN * HD;
    const float* K2bh = K2 + bh * SLEN * HD;
    const float* V2bh = V2 + bh * SLEN * HD;
    const float* r0h  = r0 + (size_t)h * NZ * HD;

    // load Q tile (32x64)
#pragma unroll
    for (int i = 0; i < 8; i++) {
        int o = t + 256 * i;
        Qs[o >> 6][o & 63] = Qbh[(size_t)(q0 + (o >> 6)) * HD + (o & 63)];
    }
    if (t < 32) { mrow[t] = -1e30f; lrow[t] = 0.f; }
    __syncthreads();

    // qr table: qrs[qi][z] = dot(Q[qi], r0[h][z])
#pragma unroll
    for (int i = 0; i < 8; i++) {
        int o = t + 256 * i;
        int qi2 = o >> 6, z = o & 63;
        const float* rz = r0h + z * HD;
        float a = 0.f;
#pragma unroll
        for (int d = 0; d < 64; d++) a += Qs[qi2][d] * rz[d];
        qrs[qi2][z] = a;
    }
    __syncthreads();

    const int rq = t >> 4;           // 0..15 (score rows rq, rq+16)
    const int kb = (t & 15) * 4;     // score cols kb..kb+3
    const int qi = t >> 3;           // 0..31 (softmax/PV row)
    const int st = t & 7;            // sub-thread; d-block = st*8
    float acc[8];
#pragma unroll
    for (int j = 0; j < 8; j++) acc[j] = 0.f;

    const int* ridx_base = rel_idx + ((size_t)b * KTOT + SLEN + q0) * RLEN;

    for (int tile = 0; tile < 33; tile++) {
        const float* Kp; const float* Vp;
        int kk0 = 0; bool isreg;
        if (tile == 0) { Kp = K2bh; Vp = V2bh; isreg = false; }
        else {
            kk0 = (tile - 1) * 64;
            Kp = Kbh + (size_t)kk0 * HD;
            Vp = Vbh + (size_t)kk0 * HD;
            isreg = true;
        }
        // stage K,V tile (64x64 each)
#pragma unroll
        for (int i = 0; i < 4; i++) {
            int f = t + 256 * i;
            int row = f >> 4, c4 = f & 15;
            float4 kv = ((const float4*)(Kp + (size_t)row * HD))[c4];
            Ks[row][c4 * 4 + 0] = kv.x; Ks[row][c4 * 4 + 1] = kv.y;
            Ks[row][c4 * 4 + 2] = kv.z; Ks[row][c4 * 4 + 3] = kv.w;
            float4 vv = ((const float4*)(Vp + (size_t)row * HD))[c4];
            Vs[row][c4 * 4 + 0] = vv.x; Vs[row][c4 * 4 + 1] = vv.y;
            Vs[row][c4 * 4 + 2] = vv.z; Vs[row][c4 * 4 + 3] = vv.w;
        }
        __syncthreads();

        // scores
        float s0[4] = {0, 0, 0, 0}, s1[4] = {0, 0, 0, 0};
#pragma unroll
        for (int d = 0; d < 64; d++) {
            float qa = Qs[rq][d], qb = Qs[rq + 16][d];
#pragma unroll
            for (int c = 0; c < 4; c++) {
                float kv = Ks[kb + c][d];
                s0[c] += qa * kv;
                s1[c] += qb * kv;
            }
        }
        if (isreg) {
            const int* ra = ridx_base + (size_t)rq * RLEN + kk0 + kb;
            const int* rb = ridx_base + (size_t)(rq + 16) * RLEN + kk0 + kb;
            int4 ia = *(const int4*)ra;
            int4 ib = *(const int4*)rb;
            s0[0] += qrs[rq][ia.x];      s0[1] += qrs[rq][ia.y];
            s0[2] += qrs[rq][ia.z];      s0[3] += qrs[rq][ia.w];
            s1[0] += qrs[rq + 16][ib.x]; s1[1] += qrs[rq + 16][ib.y];
            s1[2] += qrs[rq + 16][ib.z]; s1[3] += qrs[rq + 16][ib.w];
        }
#pragma unroll
        for (int c = 0; c < 4; c++) {
            St[rq][kb + c] = s0[c];
            St[rq + 16][kb + c] = s1[c];
        }
        __syncthreads();

        // online softmax for row qi (8 threads per row, same wave)
        float tmax = -1e30f;
#pragma unroll
        for (int c = 0; c < 8; c++) tmax = fmaxf(tmax, St[qi][st + 8 * c]);
#pragma unroll
        for (int o = 4; o > 0; o >>= 1) tmax = fmaxf(tmax, __shfl_xor(tmax, o, 8));
        float mold = mrow[qi];
        float mnew = fmaxf(mold, tmax);
        float alpha = __expf(mold - mnew);
        float psum = 0.f;
#pragma unroll
        for (int c = 0; c < 8; c++) {
            int kk = st + 8 * c;
            float p = __expf(St[qi][kk] - mnew);
            St[qi][kk] = p;
            psum += p;
        }
#pragma unroll
        for (int o = 4; o > 0; o >>= 1) psum += __shfl_xor(psum, o, 8);
        if (st == 0) { mrow[qi] = mnew; lrow[qi] = lrow[qi] * alpha + psum; }
#pragma unroll
        for (int j = 0; j < 8; j++) acc[j] *= alpha;

        // PV
#pragma unroll 8
        for (int kk = 0; kk < 64; kk++) {
            float p = St[qi][kk];
            const float4 v0 = *(const float4*)&Vs[kk][st * 8];
            const float4 v1 = *(const float4*)&Vs[kk][st * 8 + 4];
            acc[0] += p * v0.x; acc[1] += p * v0.y;
            acc[2] += p * v0.z; acc[3] += p * v0.w;
            acc[4] += p * v1.x; acc[5] += p * v1.y;
            acc[6] += p * v1.z; acc[7] += p * v1.w;
        }
        __syncthreads();
    }

    float linv = 1.0f / lrow[qi];
    int q = q0 + qi;
    float* op = attn_out + ((size_t)q * BSZ + b) * ED + h * HD + st * 8;
#pragma unroll
    for (int j = 0; j < 8; j++) op[j] = acc[j] * linv;
}

// ------------------------------------------------------------------
extern "C" void kernel_launch(void* const* d_in, const int* in_sizes, int n_in,
                              void* d_out, int out_size, void* d_ws, size_t ws_size,
                              hipStream_t stream)
{
    const float* reg_x    = (const float*)d_in[0];
    const int*   sum_ids  = (const int*)d_in[1];
    const int*   rel_idx  = (const int*)d_in[2];
    const float* emb_sum  = (const float*)d_in[5];
    const float* rel_emb0 = (const float*)d_in[6];
    const float* Wq = (const float*)d_in[7];
    const float* bq = (const float*)d_in[8];
    const float* Wk = (const float*)d_in[9];
    const float* bk = (const float*)d_in[10];
    const float* Wv = (const float*)d_in[11];
    const float* bv = (const float*)d_in[12];
    const float* Wr0 = (const float*)d_in[13];
    const float* br0 = (const float*)d_in[14];
    const float* Wk2 = (const float*)d_in[15];
    const float* bk2 = (const float*)d_in[16];
    const float* Wv2 = (const float*)d_in[17];
    const float* bv2 = (const float*)d_in[18];
    const float* Wo  = (const float*)d_in[19];
    const float* bo  = (const float*)d_in[20];
    const float* ln_k_g  = (const float*)d_in[21];
    const float* ln_k_b  = (const float*)d_in[22];
    const float* ln_v_g  = (const float*)d_in[23];
    const float* ln_v_b  = (const float*)d_in[24];
    const float* ln_k2_g = (const float*)d_in[25];
    const float* ln_k2_b = (const float*)d_in[26];
    const float* ln_v2_g = (const float*)d_in[27];
    const float* ln_v2_b = (const float*)d_in[28];

    float* ws = (float*)d_ws;
    const size_t QKV = (size_t)BSZ * NH * RLEN * HD;   // 4,194,304
    float* q   = ws;
    float* k   = q   + QKV;
    float* v   = k   + QKV;
    float* r0  = v   + QKV;                            // 65,536
    float* sq  = r0  + (size_t)NH * NZ * HD;           // 131,072 each below
    float* sx2 = sq  + (size_t)BSZ * NH * SLEN * HD;
    float* k2  = sx2 + (size_t)BSZ * NH * SLEN * HD;
    float* v2  = k2  + (size_t)BSZ * NH * SLEN * HD;
    float* ao  = v2  + (size_t)BSZ * NH * SLEN * HD;   // 4,194,304

    const int M = RLEN * BSZ;   // 4096
    dim3 gBig(ED / 128, M / 128);   // (8, 32)

    // Q/K/V projections (head layout); Q pre-scaled by 1/sqrt(D)=0.125
    gemm128<<<gBig, 256, 0, stream>>>(reg_x, Wq, bq, q, M, ED, ED, 0.125f, 1, BSZ, RLEN);
    gemm128<<<gBig, 256, 0, stream>>>(reg_x, Wk, bk, k, M, ED, ED, 1.f,    1, BSZ, RLEN);
    gemm128<<<gBig, 256, 0, stream>>>(reg_x, Wv, bv, v, M, ED, ED, 1.f,    1, BSZ, RLEN);

    ln_heads<<<(BSZ * NH * RLEN) / 4, 256, 0, stream>>>(k, ln_k_g, ln_k_b);
    ln_heads<<<(BSZ * NH * RLEN) / 4, 256, 0, stream>>>(v, ln_v_g, ln_v_b);

    // r0 = rel_emb0 @ Wr0 + br0  -> [H][Z][D]
    gemm128<<<dim3(ED / 128, 1), 256, 0, stream>>>(rel_emb0, Wr0, br0, r0, NZ, NZ, ED, 1.f, 1, 1, NZ);

    sumq_gather<<<SLEN * BSZ, 256, 0, stream>>>(emb_sum, sum_ids, sq);

    sum_attn<<<BSZ * NH * SLEN, 256, 0, stream>>>(sq, k, v, r0, rel_idx, sx2);

    k2v2<<<BSZ * NH * SLEN, 64, 0, stream>>>(sx2, Wk2, bk2, Wv2, bv2,
                                             ln_k2_g, ln_k2_b, ln_v2_g, ln_v2_b, k2, v2);

    reg_attn<<<BSZ * NH * (RLEN / 32), 256, 0, stream>>>(q, k, v, k2, v2, r0, rel_idx, ao);

    // final projection -> d_out (R,B,E) flat
    gemm128<<<gBig, 256, 0, stream>>>(ao, Wo, bo, (float*)d_out, M, ED, ED, 1.f, 0, BSZ, RLEN);
}

// Round 2
// 1803.113 us; speedup vs baseline: 1.8302x; 1.8302x over previous
//
#include <hip/hip_runtime.h>
#include <cstdint>
#include <cstddef>

#define NH   16
#define HD   64
#define RLEN 2048
#define BSZ  2
#define SLEN 64
#define NZ   64
#define ED   1024
#define KTOT 2112   // SLEN + RLEN
#define LDK  72     // padded LDS row stride (bf16 elems) for 64-wide tiles

typedef __bf16 bf16_t;
typedef bf16_t bf16x8 __attribute__((ext_vector_type(8)));
typedef bf16_t bf16x4 __attribute__((ext_vector_type(4)));
typedef float  f32x4  __attribute__((ext_vector_type(4)));

__device__ __forceinline__ f32x4 mfma16(bf16x8 a, bf16x8 b, f32x4 c) {
    return __builtin_amdgcn_mfma_f32_16x16x32_bf16(a, b, c, 0, 0, 0);
}

// ------------------------------------------------------------------
// GEMM: C[m][n] = sum_k A[m][k]*W[k][n] + bias[n], then *scale.
// mode 0: out[m*N+n];  mode 1: head layout out[((b*NH+h)*Rr+r)*HD+d]
// obf: write bf16 instead of fp32.
// ------------------------------------------------------------------
__global__ __launch_bounds__(256) void gemm128(
    const float* __restrict__ A, const float* __restrict__ W,
    const float* __restrict__ bias, void* __restrict__ outp,
    int M, int K, int N, float scale, int mode, int obf, int Bsz, int Rr)
{
    __shared__ float As[128][17];
    __shared__ float Bs[16][129];
    const int t  = threadIdx.x;
    const int tx = t & 15, ty = t >> 4;
    const int m0 = blockIdx.y * 128, n0 = blockIdx.x * 128;

    float acc[8][8];
#pragma unroll
    for (int i = 0; i < 8; i++)
#pragma unroll
        for (int j = 0; j < 8; j++) acc[i][j] = 0.f;

    for (int k0 = 0; k0 < K; k0 += 16) {
#pragma unroll
        for (int i = 0; i < 8; i++) {
            int row = ty + i * 16;
            int m = m0 + row;
            As[row][tx] = (m < M) ? A[(size_t)m * K + k0 + tx] : 0.f;
        }
#pragma unroll
        for (int i = 0; i < 8; i++) {
            int row = (t >> 7) + i * 2, col = t & 127;
            Bs[row][col] = W[(size_t)(k0 + row) * N + n0 + col];
        }
        __syncthreads();
#pragma unroll
        for (int kk = 0; kk < 16; kk++) {
            float a[8], b[8];
#pragma unroll
            for (int i = 0; i < 8; i++) a[i] = As[ty + i * 16][kk];
#pragma unroll
            for (int j = 0; j < 8; j++) b[j] = Bs[kk][tx + j * 16];
#pragma unroll
            for (int i = 0; i < 8; i++)
#pragma unroll
                for (int j = 0; j < 8; j++) acc[i][j] += a[i] * b[j];
        }
        __syncthreads();
    }

    float* outf = (float*)outp;
    bf16_t* outb = (bf16_t*)outp;
#pragma unroll
    for (int i = 0; i < 8; i++) {
        int m = m0 + ty + i * 16;
        if (m >= M) continue;
        int r = m / Bsz, bb = m % Bsz;
#pragma unroll
        for (int j = 0; j < 8; j++) {
            int n = n0 + tx + j * 16;
            float c = (acc[i][j] + bias[n]) * scale;
            size_t off;
            if (mode == 0) off = (size_t)m * N + n;
            else {
                int h = n >> 6, d = n & 63;
                off = (((size_t)bb * NH + h) * Rr + r) * HD + d;
            }
            if (obf) outb[off] = (bf16_t)c; else outf[off] = c;
        }
    }
}

// ------------------------------------------------------------------
// In-place LayerNorm over trailing dim 64, one wave per row.
// ------------------------------------------------------------------
__global__ __launch_bounds__(256) void ln_heads(
    float* __restrict__ x, const float* __restrict__ g, const float* __restrict__ b)
{
    int row  = blockIdx.x * 4 + (threadIdx.x >> 6);
    int lane = threadIdx.x & 63;
    float v = x[(size_t)row * HD + lane];
    float s1 = v, s2 = v * v;
#pragma unroll
    for (int o = 32; o > 0; o >>= 1) {
        s1 += __shfl_xor(s1, o);
        s2 += __shfl_xor(s2, o);
    }
    float mean = s1 * (1.f / 64.f);
    float var  = s2 * (1.f / 64.f) - mean * mean;
    float y = (v - mean) * rsqrtf(var + 1e-5f) * g[lane] + b[lane];
    x[(size_t)row * HD + lane] = y;
}

// ------------------------------------------------------------------
// fp32 -> bf16, 4 elems/thread.
// ------------------------------------------------------------------
__global__ __launch_bounds__(256) void cvt_bf16(
    const float* __restrict__ src, bf16_t* __restrict__ dst, int n)
{
    int i = (blockIdx.x * 256 + threadIdx.x) * 4;
    if (i < n) {
        float4 v = *(const float4*)(src + i);
        bf16x4 o;
        o[0] = (bf16_t)v.x; o[1] = (bf16_t)v.y; o[2] = (bf16_t)v.z; o[3] = (bf16_t)v.w;
        *(bf16x4*)(dst + i) = o;
    }
}

// ------------------------------------------------------------------
// Transpose+cvt: V fp32 [bh][r][d] -> Vt bf16 [bh][d][r].
// block = (rblock, bh). 64x64 tile via LDS.
// ------------------------------------------------------------------
__global__ __launch_bounds__(256) void transpose_cvt(
    const float* __restrict__ V, bf16_t* __restrict__ Vt, int R)
{
    __shared__ float tile[64][65];
    int bh = blockIdx.y, r0 = blockIdx.x * 64;
    const float* src = V + ((size_t)bh * R + r0) * HD;
    int t = threadIdx.x;
#pragma unroll
    for (int i = 0; i < 4; i++) {
        int idx = t + i * 256;             // float4 index
        int r = idx >> 4, c = (idx & 15) * 4;
        float4 vv = *(const float4*)(src + (size_t)r * HD + c);
        tile[r][c] = vv.x; tile[r][c + 1] = vv.y; tile[r][c + 2] = vv.z; tile[r][c + 3] = vv.w;
    }
    __syncthreads();
    bf16_t* dst = Vt + (size_t)bh * HD * R + r0;
    int d = t >> 2, rs = (t & 3) * 16;
    bf16x8 o0, o1;
#pragma unroll
    for (int j = 0; j < 8; j++) {
        o0[j] = (bf16_t)tile[rs + j][d];
        o1[j] = (bf16_t)tile[rs + 8 + j][d];
    }
    *(bf16x8*)(dst + (size_t)d * R + rs) = o0;
    *(bf16x8*)(dst + (size_t)d * R + rs + 8) = o1;
}

// ------------------------------------------------------------------
// sum_q gather
// ------------------------------------------------------------------
__global__ __launch_bounds__(256) void sumq_gather(
    const float* __restrict__ emb, const int* __restrict__ ids,
    float* __restrict__ sum_q)
{
    int sb = blockIdx.x;
    int s = sb >> 1, b = sb & 1;
    int id = ids[b * SLEN + s];
    const float* src = emb + (size_t)id * ED;
    for (int e = threadIdx.x; e < ED; e += 256) {
        int h = e >> 6, d = e & 63;
        sum_q[(((size_t)b * NH + h) * SLEN + s) * HD + d] = src[e] * 0.125f;
    }
}

// ------------------------------------------------------------------
// Summary attention (fp32, unchanged this round)
// ------------------------------------------------------------------
__global__ __launch_bounds__(256) void sum_attn(
    const float* __restrict__ sum_q, const float* __restrict__ K,
    const float* __restrict__ V, const float* __restrict__ r0,
    const int* __restrict__ rel_idx, float* __restrict__ sum_x2)
{
    const int bid = blockIdx.x;
    const int s = bid & 63, h = (bid >> 6) & 15, b = bid >> 10;
    const int t = threadIdx.x;

    __shared__ __align__(16) float qs[64];
    __shared__ float qr[64];
    __shared__ float sc[2048];
    __shared__ float red[256];

    const size_t bh = (size_t)b * NH + h;
    const float* qrow = sum_q + (bh * SLEN + s) * HD;
    if (t < 64) qs[t] = qrow[t];
    __syncthreads();

    if (t < 64) {
        const float* rz = r0 + ((size_t)h * NZ + t) * HD;
        float a = 0.f;
#pragma unroll
        for (int d = 0; d < 64; d++) a += qs[d] * rz[d];
        qr[t] = a;
    }
    __syncthreads();

    const float* Kb = K + bh * RLEN * HD;
    const int* ridx = rel_idx + ((size_t)b * KTOT + s) * RLEN;
    const float4* q4 = (const float4*)qs;
    float lmax = -1e30f;
    for (int kk = t; kk < RLEN; kk += 256) {
        const float4* kr = (const float4*)(Kb + (size_t)kk * HD);
        float a = 0.f;
#pragma unroll
        for (int d4 = 0; d4 < 16; d4++) {
            float4 kv = kr[d4], qv = q4[d4];
            a += kv.x * qv.x + kv.y * qv.y + kv.z * qv.z + kv.w * qv.w;
        }
        a += qr[ridx[kk]];
        sc[kk] = a;
        lmax = fmaxf(lmax, a);
    }
    red[t] = lmax;
    __syncthreads();
    for (int o = 128; o > 0; o >>= 1) {
        if (t < o) red[t] = fmaxf(red[t], red[t + o]);
        __syncthreads();
    }
    float m = red[0];
    __syncthreads();

    float lsum = 0.f;
    for (int kk = t; kk < RLEN; kk += 256) {
        float e = __expf(sc[kk] - m);
        sc[kk] = e;
        lsum += e;
    }
    red[t] = lsum;
    __syncthreads();
    for (int o = 128; o > 0; o >>= 1) {
        if (t < o) red[t] += red[t + o];
        __syncthreads();
    }
    float linv = 1.0f / red[0];
    __syncthreads();

    const float* Vb = V + bh * RLEN * HD;
    int d = t & 63, c = t >> 6;
    float acc = 0.f;
    for (int kk = c * 512; kk < (c + 1) * 512; kk++)
        acc += sc[kk] * Vb[(size_t)kk * HD + d];
    red[t] = acc;
    __syncthreads();
    if (t < 64) {
        float o = (red[t] + red[t + 64] + red[t + 128] + red[t + 192]) * linv;
        sum_x2[(bh * SLEN + s) * HD + t] = o;
    }
}

// ------------------------------------------------------------------
// sum_k2 / sum_v2: y = LN(x @ W + b); write bf16 K2 [bh][s][d] and
// transposed bf16 V2t [bh][d][s]. One wave per row.
// ------------------------------------------------------------------
__global__ __launch_bounds__(64) void k2v2(
    const float* __restrict__ sum_x2,
    const float* __restrict__ Wk2, const float* __restrict__ bk2,
    const float* __restrict__ Wv2, const float* __restrict__ bv2,
    const float* __restrict__ gk, const float* __restrict__ bk,
    const float* __restrict__ gv, const float* __restrict__ bv,
    bf16_t* __restrict__ k2b, bf16_t* __restrict__ v2tb)
{
    int row = blockIdx.x;              // bh*64 + s
    int d = threadIdx.x;
    int bh = row >> 6, s = row & 63;
    __shared__ float xs[64];
    xs[d] = sum_x2[(size_t)row * HD + d];
    __syncthreads();

#pragma unroll
    for (int which = 0; which < 2; which++) {
        const float* W  = which ? Wv2 : Wk2;
        const float* bi = which ? bv2 : bk2;
        const float* g  = which ? gv : gk;
        const float* bb = which ? bv : bk;
        float a = bi[d];
#pragma unroll
        for (int j = 0; j < 64; j++) a += xs[j] * W[j * HD + d];
        float s1 = a, s2 = a * a;
#pragma unroll
        for (int o = 32; o > 0; o >>= 1) {
            s1 += __shfl_xor(s1, o);
            s2 += __shfl_xor(s2, o);
        }
        float mean = s1 * (1.f / 64.f);
        float var  = s2 * (1.f / 64.f) - mean * mean;
        float y = (a - mean) * rsqrtf(var + 1e-5f) * g[d] + bb[d];
        if (which == 0) k2b[(size_t)row * HD + d] = (bf16_t)y;
        else            v2tb[(size_t)bh * (HD * SLEN) + d * SLEN + s] = (bf16_t)y;
    }
}

// ------------------------------------------------------------------
// Main attention, MFMA flash. Block = (b,h, 64-q-row tile), 4 waves.
// Wave w owns q rows [w*16, w*16+16). 33 key tiles of 64.
// ------------------------------------------------------------------
__global__ __launch_bounds__(256) void reg_attn_mfma(
    const bf16_t* __restrict__ Qb,   // [bh][r][d]
    const bf16_t* __restrict__ Kb,   // [bh][r][d]
    const bf16_t* __restrict__ Vtb,  // [bh][d][r]
    const bf16_t* __restrict__ K2b,  // [bh][s][d]
    const bf16_t* __restrict__ V2tb, // [bh][d][s]
    const float*  __restrict__ r0,   // [h][z][d] fp32
    const int*    __restrict__ rel_idx,
    float* __restrict__ attn_out)    // [r][b][E]
{
    // XCD-aware swizzle: all 32 q-tiles of 4 (b,h) pairs per XCD
    const int bid = blockIdx.x;
    const int bh = (bid & 7) * 4 + ((bid >> 3) & 3);
    const int qt = bid >> 5;
    const int b = bh >> 4, h = bh & 15;
    const int q0 = qt * 64;

    const int t = threadIdx.x;
    const int wave = t >> 6, lane = t & 63;
    const int quad = lane >> 4, l15 = lane & 15;

    __shared__ __align__(16) bf16_t Ks[64 * LDK];
    __shared__ __align__(16) bf16_t Vs[64 * LDK];
    __shared__ __align__(16) bf16_t Ps[64 * LDK];
    __shared__ __align__(16) bf16_t qrs[64 * 64];

    // ---- Q fragments (held all kernel) ----
    const bf16_t* Qrow = Qb + (((size_t)bh * RLEN) + q0 + wave * 16 + l15) * HD;
    bf16x8 qf0 = *(const bf16x8*)(Qrow + quad * 8);
    bf16x8 qf1 = *(const bf16x8*)(Qrow + 32 + quad * 8);

    // ---- qr table via MFMA: qrs[qlocal][z] = Q[q]·r0[h][z] ----
    {
#pragma unroll
        for (int nt = 0; nt < 4; nt++) {
            f32x4 qa = {0.f, 0.f, 0.f, 0.f};
            const float* rp = r0 + ((size_t)h * NZ + l15 + 16 * nt) * HD + quad * 8;
            float4 a0 = *(const float4*)(rp);
            float4 a1 = *(const float4*)(rp + 4);
            bf16x8 bf;
            bf[0] = (bf16_t)a0.x; bf[1] = (bf16_t)a0.y; bf[2] = (bf16_t)a0.z; bf[3] = (bf16_t)a0.w;
            bf[4] = (bf16_t)a1.x; bf[5] = (bf16_t)a1.y; bf[6] = (bf16_t)a1.z; bf[7] = (bf16_t)a1.w;
            qa = mfma16(qf0, bf, qa);
            float4 b0 = *(const float4*)(rp + 32);
            float4 b1 = *(const float4*)(rp + 36);
            bf[0] = (bf16_t)b0.x; bf[1] = (bf16_t)b0.y; bf[2] = (bf16_t)b0.z; bf[3] = (bf16_t)b0.w;
            bf[4] = (bf16_t)b1.x; bf[5] = (bf16_t)b1.y; bf[6] = (bf16_t)b1.z; bf[7] = (bf16_t)b1.w;
            qa = mfma16(qf1, bf, qa);
#pragma unroll
            for (int reg = 0; reg < 4; reg++)
                qrs[(wave * 16 + quad * 4 + reg) * 64 + l15 + 16 * nt] = (bf16_t)qa[reg];
        }
    }

    f32x4 O[4];
    float m_i[4], l_i[4];
#pragma unroll
    for (int nt = 0; nt < 4; nt++) O[nt] = (f32x4){0.f, 0.f, 0.f, 0.f};
#pragma unroll
    for (int r = 0; r < 4; r++) { m_i[r] = -1e30f; l_i[r] = 0.f; }

    const int srow = t >> 2;            // staging row 0..63
    const int scol = (t & 3) * 16;      // staging col seg

    for (int tile = 0; tile < 33; tile++) {
        const bf16_t* Kt; const bf16_t* Vt;
        size_t vstr; int kk0 = 0;
        if (tile == 0) {
            Kt = K2b + (size_t)bh * (SLEN * HD);
            Vt = V2tb + (size_t)bh * (HD * SLEN);
            vstr = SLEN;
        } else {
            kk0 = (tile - 1) * 64;
            Kt = Kb + ((size_t)bh * RLEN + kk0) * HD;
            Vt = Vtb + (size_t)bh * HD * RLEN + kk0;
            vstr = RLEN;
        }
        // stage K [key][d] and Vt [d][key] tiles into padded LDS
        {
            const bf16x8* ks = (const bf16x8*)(Kt + (size_t)srow * HD + scol);
            bf16x8 a0 = ks[0], a1 = ks[1];
            const bf16x8* vs = (const bf16x8*)(Vt + (size_t)srow * vstr + scol);
            bf16x8 v0 = vs[0], v1 = vs[1];
            *(bf16x8*)(Ks + srow * LDK + scol)     = a0;
            *(bf16x8*)(Ks + srow * LDK + scol + 8) = a1;
            *(bf16x8*)(Vs + srow * LDK + scol)     = v0;
            *(bf16x8*)(Vs + srow * LDK + scol + 8) = v1;
        }
        __syncthreads();

        // ---- S = Q K^T (16 q-rows x 64 keys per wave) ----
        f32x4 S[4];
#pragma unroll
        for (int nt = 0; nt < 4; nt++) {
            f32x4 acc = {0.f, 0.f, 0.f, 0.f};
            bf16x8 kf0 = *(const bf16x8*)(Ks + (l15 + 16 * nt) * LDK + quad * 8);
            bf16x8 kf1 = *(const bf16x8*)(Ks + (l15 + 16 * nt) * LDK + 32 + quad * 8);
            acc = mfma16(qf0, kf0, acc);
            acc = mfma16(qf1, kf1, acc);
            S[nt] = acc;
        }

        // ---- rel-pos bias ----
        if (tile > 0) {
            const int* rrow = rel_idx + ((size_t)b * KTOT + SLEN + q0 + wave * 16 + quad * 4) * RLEN
                              + kk0 + l15;
#pragma unroll
            for (int reg = 0; reg < 4; reg++) {
                const int* rp = rrow + (size_t)reg * RLEN;
                int qlocal = wave * 16 + quad * 4 + reg;
#pragma unroll
                for (int nt = 0; nt < 4; nt++) {
                    int idx = rp[16 * nt];
                    S[nt][reg] += (float)qrs[qlocal * 64 + idx];
                }
            }
        }

        // ---- online softmax (per-row over 16-lane groups) ----
        float tmax[4];
#pragma unroll
        for (int reg = 0; reg < 4; reg++) {
            float v = fmaxf(fmaxf(S[0][reg], S[1][reg]), fmaxf(S[2][reg], S[3][reg]));
#pragma unroll
            for (int o = 8; o > 0; o >>= 1) v = fmaxf(v, __shfl_xor(v, o));
            tmax[reg] = v;
        }
        float alpha[4], psum[4];
#pragma unroll
        for (int reg = 0; reg < 4; reg++) {
            float mn = fmaxf(m_i[reg], tmax[reg]);
            alpha[reg] = __expf(m_i[reg] - mn);
            m_i[reg] = mn;
            psum[reg] = 0.f;
        }
#pragma unroll
        for (int nt = 0; nt < 4; nt++)
#pragma unroll
            for (int reg = 0; reg < 4; reg++) {
                float p = __expf(S[nt][reg] - m_i[reg]);
                S[nt][reg] = p;
                psum[reg] += p;
            }
#pragma unroll
        for (int reg = 0; reg < 4; reg++) {
#pragma unroll
            for (int o = 8; o > 0; o >>= 1) psum[reg] += __shfl_xor(psum[reg], o);
            l_i[reg] = l_i[reg] * alpha[reg] + psum[reg];
        }
#pragma unroll
        for (int nt = 0; nt < 4; nt++) {
            O[nt][0] *= alpha[0]; O[nt][1] *= alpha[1];
            O[nt][2] *= alpha[2]; O[nt][3] *= alpha[3];
        }

        // ---- P -> LDS (own wave strip), then PV ----
#pragma unroll
        for (int nt = 0; nt < 4; nt++)
#pragma unroll
            for (int reg = 0; reg < 4; reg++)
                Ps[(wave * 16 + quad * 4 + reg) * LDK + l15 + 16 * nt] = (bf16_t)S[nt][reg];

        bf16x8 pf0 = *(const bf16x8*)(Ps + (wave * 16 + l15) * LDK + quad * 8);
        bf16x8 pf1 = *(const bf16x8*)(Ps + (wave * 16 + l15) * LDK + 32 + quad * 8);
#pragma unroll
        for (int nt = 0; nt < 4; nt++) {
            bf16x8 vf0 = *(const bf16x8*)(Vs + (l15 + 16 * nt) * LDK + quad * 8);
            bf16x8 vf1 = *(const bf16x8*)(Vs + (l15 + 16 * nt) * LDK + 32 + quad * 8);
            O[nt] = mfma16(pf0, vf0, O[nt]);
            O[nt] = mfma16(pf1, vf1, O[nt]);
        }
        __syncthreads();
    }

    // ---- epilogue ----
    float linv[4];
#pragma unroll
    for (int reg = 0; reg < 4; reg++) linv[reg] = 1.0f / l_i[reg];
#pragma unroll
    for (int nt = 0; nt < 4; nt++)
#pragma unroll
        for (int reg = 0; reg < 4; reg++) {
            int q = q0 + wave * 16 + quad * 4 + reg;
            attn_out[((size_t)q * BSZ + b) * ED + h * HD + l15 + 16 * nt] = O[nt][reg] * linv[reg];
        }
}

// ------------------------------------------------------------------
extern "C" void kernel_launch(void* const* d_in, const int* in_sizes, int n_in,
                              void* d_out, int out_size, void* d_ws, size_t ws_size,
                              hipStream_t stream)
{
    const float* reg_x    = (const float*)d_in[0];
    const int*   sum_ids  = (const int*)d_in[1];
    const int*   rel_idx  = (const int*)d_in[2];
    const float* emb_sum  = (const float*)d_in[5];
    const float* rel_emb0 = (const float*)d_in[6];
    const float* Wq = (const float*)d_in[7];
    const float* bq = (const float*)d_in[8];
    const float* Wk = (const float*)d_in[9];
    const float* bk = (const float*)d_in[10];
    const float* Wv = (const float*)d_in[11];
    const float* bv = (const float*)d_in[12];
    const float* Wr0 = (const float*)d_in[13];
    const float* br0 = (const float*)d_in[14];
    const float* Wk2 = (const float*)d_in[15];
    const float* bk2 = (const float*)d_in[16];
    const float* Wv2 = (const float*)d_in[17];
    const float* bv2 = (const float*)d_in[18];
    const float* Wo  = (const float*)d_in[19];
    const float* bo  = (const float*)d_in[20];
    const float* ln_k_g  = (const float*)d_in[21];
    const float* ln_k_b  = (const float*)d_in[22];
    const float* ln_v_g  = (const float*)d_in[23];
    const float* ln_v_b  = (const float*)d_in[24];
    const float* ln_k2_g = (const float*)d_in[25];
    const float* ln_k2_b = (const float*)d_in[26];
    const float* ln_v2_g = (const float*)d_in[27];
    const float* ln_v2_b = (const float*)d_in[28];

    float* ws = (float*)d_ws;
    const size_t QKV = (size_t)BSZ * NH * RLEN * HD;   // 4,194,304
    float* k   = ws;
    float* v   = k   + QKV;
    float* r0  = v   + QKV;                            // 65,536
    float* sq  = r0  + (size_t)NH * NZ * HD;
    float* sx2 = sq  + (size_t)BSZ * NH * SLEN * HD;
    float* ao  = sx2 + (size_t)BSZ * NH * SLEN * HD;   // 4,194,304
    bf16_t* qb   = (bf16_t*)(ao + QKV);                // 4M bf16
    bf16_t* kb   = qb + QKV;
    bf16_t* vtb  = kb + QKV;
    bf16_t* k2b  = vtb + QKV;                          // 131,072 bf16
    bf16_t* v2tb = k2b + (size_t)BSZ * NH * SLEN * HD;

    const int M = RLEN * BSZ;   // 4096
    dim3 gBig(ED / 128, M / 128);

    // Projections: Q straight to bf16 (scaled); K,V fp32 for LN
    gemm128<<<gBig, 256, 0, stream>>>(reg_x, Wq, bq, qb, M, ED, ED, 0.125f, 1, 1, BSZ, RLEN);
    gemm128<<<gBig, 256, 0, stream>>>(reg_x, Wk, bk, k,  M, ED, ED, 1.f,    1, 0, BSZ, RLEN);
    gemm128<<<gBig, 256, 0, stream>>>(reg_x, Wv, bv, v,  M, ED, ED, 1.f,    1, 0, BSZ, RLEN);

    ln_heads<<<(BSZ * NH * RLEN) / 4, 256, 0, stream>>>(k, ln_k_g, ln_k_b);
    ln_heads<<<(BSZ * NH * RLEN) / 4, 256, 0, stream>>>(v, ln_v_g, ln_v_b);

    cvt_bf16<<<(int)(QKV / 1024), 256, 0, stream>>>(k, kb, (int)QKV);
    transpose_cvt<<<dim3(RLEN / 64, BSZ * NH), 256, 0, stream>>>(v, vtb, RLEN);

    gemm128<<<dim3(ED / 128, 1), 256, 0, stream>>>(rel_emb0, Wr0, br0, r0, NZ, NZ, ED, 1.f, 1, 0, 1, NZ);

    sumq_gather<<<SLEN * BSZ, 256, 0, stream>>>(emb_sum, sum_ids, sq);

    sum_attn<<<BSZ * NH * SLEN, 256, 0, stream>>>(sq, k, v, r0, rel_idx, sx2);

    k2v2<<<BSZ * NH * SLEN, 64, 0, stream>>>(sx2, Wk2, bk2, Wv2, bv2,
                                             ln_k2_g, ln_k2_b, ln_v2_g, ln_v2_b, k2b, v2tb);

    reg_attn_mfma<<<BSZ * NH * (RLEN / 64), 256, 0, stream>>>(qb, kb, vtb, k2b, v2tb,
                                                              r0, rel_idx, ao);

    gemm128<<<gBig, 256, 0, stream>>>(ao, Wo, bo, (float*)d_out, M, ED, ED, 1.f, 0, 0, BSZ, RLEN);
}

// Round 3
// 722.651 us; speedup vs baseline: 4.5667x; 2.4951x over previous
//
#include <hip/hip_runtime.h>
#include <cstdint>
#include <cstddef>

#define NH   16
#define HD   64
#define RLEN 2048
#define BSZ  2
#define SLEN 64
#define NZ   64
#define ED   1024
#define KTOT 2112   // SLEN + RLEN
#define LDK  72     // padded LDS row stride (bf16) for attention tiles

typedef __bf16 bf16_t;
typedef bf16_t bf16x8 __attribute__((ext_vector_type(8)));
typedef bf16_t bf16x4 __attribute__((ext_vector_type(4)));
typedef float  f32x4  __attribute__((ext_vector_type(4)));

__device__ __forceinline__ f32x4 mfma16(bf16x8 a, bf16x8 b, f32x4 c) {
    return __builtin_amdgcn_mfma_f32_16x16x32_bf16(a, b, c, 0, 0, 0);
}

// ------------------------------------------------------------------
// bf16 MFMA GEMM. A bf16 [M][K], Bt bf16 [N][K] (pre-transposed),
// bias fp32 [N]. C = (A@B + bias) * scale.
// mode 0: out[m*N+n]; mode 1: head layout out[((bb*NH+h)*Rr+r)*HD+d]
// with r=m/Bsz, bb=m%Bsz, h=n>>6, d=n&63. obf: bf16 output.
// Tile 64(M)x128(N), BK=32, 4 waves each 32x64.
// ------------------------------------------------------------------
__global__ __launch_bounds__(256) void gemm_mfma(
    const bf16_t* __restrict__ A, const bf16_t* __restrict__ Bt,
    const float* __restrict__ bias, void* __restrict__ outp,
    int M, int K, int N, float scale, int mode, int obf, int Bsz, int Rr)
{
    constexpr int LDA = 40;
    __shared__ __align__(16) bf16_t As[64 * LDA];
    __shared__ __align__(16) bf16_t Bs[128 * LDA];

    const int t = threadIdx.x;
    const int wave = t >> 6, lane = t & 63;
    const int quad = lane >> 4, l15 = lane & 15;
    const int wrow = wave >> 1, wcol = wave & 1;
    const int m0 = blockIdx.y * 64, n0 = blockIdx.x * 128;

    f32x4 acc[2][4];
#pragma unroll
    for (int i = 0; i < 2; i++)
#pragma unroll
        for (int j = 0; j < 4; j++) acc[i][j] = (f32x4){0.f, 0.f, 0.f, 0.f};

    const int srow = t >> 2, sseg = (t & 3) * 8;

    for (int k0 = 0; k0 < K; k0 += 32) {
        bf16x8 av  = *(const bf16x8*)(A  + (size_t)(m0 + srow) * K + k0 + sseg);
        bf16x8 bv0 = *(const bf16x8*)(Bt + (size_t)(n0 + srow) * K + k0 + sseg);
        bf16x8 bv1 = *(const bf16x8*)(Bt + (size_t)(n0 + 64 + srow) * K + k0 + sseg);
        __syncthreads();
        *(bf16x8*)(As + srow * LDA + sseg)        = av;
        *(bf16x8*)(Bs + srow * LDA + sseg)        = bv0;
        *(bf16x8*)(Bs + (64 + srow) * LDA + sseg) = bv1;
        __syncthreads();

        bf16x8 af[2], bf[4];
#pragma unroll
        for (int mt = 0; mt < 2; mt++)
            af[mt] = *(const bf16x8*)(As + (wrow * 32 + mt * 16 + l15) * LDA + quad * 8);
#pragma unroll
        for (int nt = 0; nt < 4; nt++)
            bf[nt] = *(const bf16x8*)(Bs + (wcol * 64 + nt * 16 + l15) * LDA + quad * 8);
#pragma unroll
        for (int mt = 0; mt < 2; mt++)
#pragma unroll
            for (int nt = 0; nt < 4; nt++)
                acc[mt][nt] = mfma16(af[mt], bf[nt], acc[mt][nt]);
    }

    float* outf = (float*)outp;
    bf16_t* outb = (bf16_t*)outp;
#pragma unroll
    for (int mt = 0; mt < 2; mt++)
#pragma unroll
        for (int nt = 0; nt < 4; nt++)
#pragma unroll
            for (int reg = 0; reg < 4; reg++) {
                int m = m0 + wrow * 32 + mt * 16 + quad * 4 + reg;
                int n = n0 + wcol * 64 + nt * 16 + l15;
                if (m >= M) continue;
                float c = (acc[mt][nt][reg] + bias[n]) * scale;
                size_t off;
                if (mode == 0) off = (size_t)m * N + n;
                else {
                    int h = n >> 6, d = n & 63;
                    int r = m / Bsz, bb = m % Bsz;
                    off = (((size_t)bb * NH + h) * Rr + r) * HD + d;
                }
                if (obf) outb[off] = (bf16_t)c; else outf[off] = c;
            }
}

// ------------------------------------------------------------------
// LayerNorm over trailing 64, one wave per row. to_bf16: write outb
// instead of in-place fp32.
// ------------------------------------------------------------------
__global__ __launch_bounds__(256) void ln_heads(
    float* __restrict__ x, const float* __restrict__ g, const float* __restrict__ b,
    bf16_t* __restrict__ outb, int to_bf16)
{
    int row  = blockIdx.x * 4 + (threadIdx.x >> 6);
    int lane = threadIdx.x & 63;
    float v = x[(size_t)row * HD + lane];
    float s1 = v, s2 = v * v;
#pragma unroll
    for (int o = 32; o > 0; o >>= 1) {
        s1 += __shfl_xor(s1, o);
        s2 += __shfl_xor(s2, o);
    }
    float mean = s1 * (1.f / 64.f);
    float var  = s2 * (1.f / 64.f) - mean * mean;
    float y = (v - mean) * rsqrtf(var + 1e-5f) * g[lane] + b[lane];
    if (to_bf16) outb[(size_t)row * HD + lane] = (bf16_t)y;
    else         x[(size_t)row * HD + lane] = y;
}

// ------------------------------------------------------------------
// fp32 -> bf16, 4 elems/thread.
// ------------------------------------------------------------------
__global__ __launch_bounds__(256) void cvt_bf16(
    const float* __restrict__ src, bf16_t* __restrict__ dst, int n)
{
    int i = (blockIdx.x * 256 + threadIdx.x) * 4;
    if (i < n) {
        float4 v = *(const float4*)(src + i);
        bf16x4 o;
        o[0] = (bf16_t)v.x; o[1] = (bf16_t)v.y; o[2] = (bf16_t)v.z; o[3] = (bf16_t)v.w;
        *(bf16x4*)(dst + i) = o;
    }
}

// ------------------------------------------------------------------
// Per-bh transpose+cvt: V fp32 [bh][r][d] -> Vt bf16 [bh][d][r].
// ------------------------------------------------------------------
__global__ __launch_bounds__(256) void transpose_cvt(
    const float* __restrict__ V, bf16_t* __restrict__ Vt, int R)
{
    __shared__ float tile[64][65];
    int bh = blockIdx.y, r0 = blockIdx.x * 64;
    const float* src = V + ((size_t)bh * R + r0) * HD;
    int t = threadIdx.x;
#pragma unroll
    for (int i = 0; i < 4; i++) {
        int idx = t + i * 256;
        int r = idx >> 4, c = (idx & 15) * 4;
        float4 vv = *(const float4*)(src + (size_t)r * HD + c);
        tile[r][c] = vv.x; tile[r][c + 1] = vv.y; tile[r][c + 2] = vv.z; tile[r][c + 3] = vv.w;
    }
    __syncthreads();
    bf16_t* dst = Vt + (size_t)bh * HD * R + r0;
    int d = t >> 2, rs = (t & 3) * 16;
    bf16x8 o0, o1;
#pragma unroll
    for (int j = 0; j < 8; j++) {
        o0[j] = (bf16_t)tile[rs + j][d];
        o1[j] = (bf16_t)tile[rs + 8 + j][d];
    }
    *(bf16x8*)(dst + (size_t)d * R + rs) = o0;
    *(bf16x8*)(dst + (size_t)d * R + rs + 8) = o1;
}

// ------------------------------------------------------------------
// Generic transpose+cvt: src fp32 [R][C] -> dst bf16 [C][R].
// R, C multiples of 64. grid (C/64, R/64).
// ------------------------------------------------------------------
__global__ __launch_bounds__(256) void transpose_cvt2(
    const float* __restrict__ src, bf16_t* __restrict__ dst, int R, int C)
{
    __shared__ float tile[64][65];
    int r0 = blockIdx.y * 64, c0 = blockIdx.x * 64;
    int t = threadIdx.x;
#pragma unroll
    for (int i = 0; i < 4; i++) {
        int idx = t + i * 256;
        int r = idx >> 4, c = (idx & 15) * 4;
        float4 vv = *(const float4*)(src + (size_t)(r0 + r) * C + c0 + c);
        tile[r][c] = vv.x; tile[r][c + 1] = vv.y; tile[r][c + 2] = vv.z; tile[r][c + 3] = vv.w;
    }
    __syncthreads();
    int cc = t >> 2, rs = (t & 3) * 16;
    bf16x8 o0, o1;
#pragma unroll
    for (int j = 0; j < 8; j++) {
        o0[j] = (bf16_t)tile[rs + j][cc];
        o1[j] = (bf16_t)tile[rs + 8 + j][cc];
    }
    *(bf16x8*)(dst + (size_t)(c0 + cc) * R + r0 + rs) = o0;
    *(bf16x8*)(dst + (size_t)(c0 + cc) * R + r0 + rs + 8) = o1;
}

// ------------------------------------------------------------------
// sum_q gather -> bf16, pre-scaled.
// ------------------------------------------------------------------
__global__ __launch_bounds__(256) void sumq_gather(
    const float* __restrict__ emb, const int* __restrict__ ids,
    bf16_t* __restrict__ sum_q)
{
    int sb = blockIdx.x;
    int s = sb >> 1, b = sb & 1;
    int id = ids[b * SLEN + s];
    const float* src = emb + (size_t)id * ED;
    for (int e = threadIdx.x; e < ED; e += 256) {
        int h = e >> 6, d = e & 63;
        sum_q[(((size_t)b * NH + h) * SLEN + s) * HD + d] = (bf16_t)(src[e] * 0.125f);
    }
}

// ------------------------------------------------------------------
// Summary attention, MFMA flash. One block per (b,h); 4 waves x 16 s-rows;
// 32 reg-key tiles of 64. rel bias rows = rel_idx[:, :S].
// ------------------------------------------------------------------
__global__ __launch_bounds__(256) void sum_attn_mfma(
    const bf16_t* __restrict__ Qb,   // sum_q [bh][s][d]
    const bf16_t* __restrict__ Kb,   // [bh][r][d]
    const bf16_t* __restrict__ Vtb,  // [bh][d][r]
    const float*  __restrict__ r0,   // [h][z][d]
    const int*    __restrict__ rel_idx,
    float* __restrict__ sum_x2)      // [bh][s][d]
{
    const int bh = blockIdx.x;
    const int b = bh >> 4, h = bh & 15;
    const int t = threadIdx.x;
    const int wave = t >> 6, lane = t & 63;
    const int quad = lane >> 4, l15 = lane & 15;

    __shared__ __align__(16) bf16_t Ks[64 * LDK];
    __shared__ __align__(16) bf16_t Vs[64 * LDK];
    __shared__ __align__(16) bf16_t Ps[64 * LDK];
    __shared__ __align__(16) bf16_t qrs[64 * 64];

    const bf16_t* Qrow = Qb + ((size_t)bh * SLEN + wave * 16 + l15) * HD;
    bf16x8 qf0 = *(const bf16x8*)(Qrow + quad * 8);
    bf16x8 qf1 = *(const bf16x8*)(Qrow + 32 + quad * 8);

#pragma unroll
    for (int nt = 0; nt < 4; nt++) {
        f32x4 qa = {0.f, 0.f, 0.f, 0.f};
        const float* rp = r0 + ((size_t)h * NZ + l15 + 16 * nt) * HD + quad * 8;
        float4 a0 = *(const float4*)(rp);
        float4 a1 = *(const float4*)(rp + 4);
        bf16x8 bf;
        bf[0] = (bf16_t)a0.x; bf[1] = (bf16_t)a0.y; bf[2] = (bf16_t)a0.z; bf[3] = (bf16_t)a0.w;
        bf[4] = (bf16_t)a1.x; bf[5] = (bf16_t)a1.y; bf[6] = (bf16_t)a1.z; bf[7] = (bf16_t)a1.w;
        qa = mfma16(qf0, bf, qa);
        float4 b0 = *(const float4*)(rp + 32);
        float4 b1 = *(const float4*)(rp + 36);
        bf[0] = (bf16_t)b0.x; bf[1] = (bf16_t)b0.y; bf[2] = (bf16_t)b0.z; bf[3] = (bf16_t)b0.w;
        bf[4] = (bf16_t)b1.x; bf[5] = (bf16_t)b1.y; bf[6] = (bf16_t)b1.z; bf[7] = (bf16_t)b1.w;
        qa = mfma16(qf1, bf, qa);
#pragma unroll
        for (int reg = 0; reg < 4; reg++)
            qrs[(wave * 16 + quad * 4 + reg) * 64 + l15 + 16 * nt] = (bf16_t)qa[reg];
    }

    f32x4 O[4];
    float m_i[4], l_i[4];
#pragma unroll
    for (int nt = 0; nt < 4; nt++) O[nt] = (f32x4){0.f, 0.f, 0.f, 0.f};
#pragma unroll
    for (int r = 0; r < 4; r++) { m_i[r] = -1e30f; l_i[r] = 0.f; }

    const int srow = t >> 2;
    const int scol = (t & 3) * 16;

    for (int tile = 0; tile < 32; tile++) {
        const int kk0 = tile * 64;
        const bf16_t* Kt = Kb + ((size_t)bh * RLEN + kk0) * HD;
        const bf16_t* Vt = Vtb + (size_t)bh * HD * RLEN + kk0;
        {
            const bf16x8* ks = (const bf16x8*)(Kt + (size_t)srow * HD + scol);
            bf16x8 a0 = ks[0], a1 = ks[1];
            const bf16x8* vs = (const bf16x8*)(Vt + (size_t)srow * RLEN + scol);
            bf16x8 v0 = vs[0], v1 = vs[1];
            *(bf16x8*)(Ks + srow * LDK + scol)     = a0;
            *(bf16x8*)(Ks + srow * LDK + scol + 8) = a1;
            *(bf16x8*)(Vs + srow * LDK + scol)     = v0;
            *(bf16x8*)(Vs + srow * LDK + scol + 8) = v1;
        }
        __syncthreads();

        f32x4 S[4];
#pragma unroll
        for (int nt = 0; nt < 4; nt++) {
            f32x4 acc = {0.f, 0.f, 0.f, 0.f};
            bf16x8 kf0 = *(const bf16x8*)(Ks + (l15 + 16 * nt) * LDK + quad * 8);
            bf16x8 kf1 = *(const bf16x8*)(Ks + (l15 + 16 * nt) * LDK + 32 + quad * 8);
            acc = mfma16(qf0, kf0, acc);
            acc = mfma16(qf1, kf1, acc);
            S[nt] = acc;
        }

        const int* rrow = rel_idx + ((size_t)b * KTOT + wave * 16 + quad * 4) * RLEN + kk0 + l15;
#pragma unroll
        for (int reg = 0; reg < 4; reg++) {
            const int* rp = rrow + (size_t)reg * RLEN;
            int qlocal = wave * 16 + quad * 4 + reg;
#pragma unroll
            for (int nt = 0; nt < 4; nt++) {
                int idx = rp[16 * nt];
                S[nt][reg] += (float)qrs[qlocal * 64 + idx];
            }
        }

        float tmax[4];
#pragma unroll
        for (int reg = 0; reg < 4; reg++) {
            float v = fmaxf(fmaxf(S[0][reg], S[1][reg]), fmaxf(S[2][reg], S[3][reg]));
#pragma unroll
            for (int o = 8; o > 0; o >>= 1) v = fmaxf(v, __shfl_xor(v, o));
            tmax[reg] = v;
        }
        float alpha[4], psum[4];
#pragma unroll
        for (int reg = 0; reg < 4; reg++) {
            float mn = fmaxf(m_i[reg], tmax[reg]);
            alpha[reg] = __expf(m_i[reg] - mn);
            m_i[reg] = mn;
            psum[reg] = 0.f;
        }
#pragma unroll
        for (int nt = 0; nt < 4; nt++)
#pragma unroll
            for (int reg = 0; reg < 4; reg++) {
                float p = __expf(S[nt][reg] - m_i[reg]);
                S[nt][reg] = p;
                psum[reg] += p;
            }
#pragma unroll
        for (int reg = 0; reg < 4; reg++) {
#pragma unroll
            for (int o = 8; o > 0; o >>= 1) psum[reg] += __shfl_xor(psum[reg], o);
            l_i[reg] = l_i[reg] * alpha[reg] + psum[reg];
        }
#pragma unroll
        for (int nt = 0; nt < 4; nt++) {
            O[nt][0] *= alpha[0]; O[nt][1] *= alpha[1];
            O[nt][2] *= alpha[2]; O[nt][3] *= alpha[3];
        }

#pragma unroll
        for (int nt = 0; nt < 4; nt++)
#pragma unroll
            for (int reg = 0; reg < 4; reg++)
                Ps[(wave * 16 + quad * 4 + reg) * LDK + l15 + 16 * nt] = (bf16_t)S[nt][reg];

        bf16x8 pf0 = *(const bf16x8*)(Ps + (wave * 16 + l15) * LDK + quad * 8);
        bf16x8 pf1 = *(const bf16x8*)(Ps + (wave * 16 + l15) * LDK + 32 + quad * 8);
#pragma unroll
        for (int nt = 0; nt < 4; nt++) {
            bf16x8 vf0 = *(const bf16x8*)(Vs + (l15 + 16 * nt) * LDK + quad * 8);
            bf16x8 vf1 = *(const bf16x8*)(Vs + (l15 + 16 * nt) * LDK + 32 + quad * 8);
            O[nt] = mfma16(pf0, vf0, O[nt]);
            O[nt] = mfma16(pf1, vf1, O[nt]);
        }
        __syncthreads();
    }

    float linv[4];
#pragma unroll
    for (int reg = 0; reg < 4; reg++) linv[reg] = 1.0f / l_i[reg];
#pragma unroll
    for (int nt = 0; nt < 4; nt++)
#pragma unroll
        for (int reg = 0; reg < 4; reg++) {
            int sq = wave * 16 + quad * 4 + reg;
            sum_x2[((size_t)bh * SLEN + sq) * HD + l15 + 16 * nt] = O[nt][reg] * linv[reg];
        }
}

// ------------------------------------------------------------------
// sum_k2 / sum_v2: y = LN(x @ W + b); bf16 K2 [bh][s][d], V2t [bh][d][s].
// ------------------------------------------------------------------
__global__ __launch_bounds__(64) void k2v2(
    const float* __restrict__ sum_x2,
    const float* __restrict__ Wk2, const float* __restrict__ bk2,
    const float* __restrict__ Wv2, const float* __restrict__ bv2,
    const float* __restrict__ gk, const float* __restrict__ bk,
    const float* __restrict__ gv, const float* __restrict__ bv,
    bf16_t* __restrict__ k2b, bf16_t* __restrict__ v2tb)
{
    int row = blockIdx.x;              // bh*64 + s
    int d = threadIdx.x;
    int bh = row >> 6, s = row & 63;
    __shared__ float xs[64];
    xs[d] = sum_x2[(size_t)row * HD + d];
    __syncthreads();

#pragma unroll
    for (int which = 0; which < 2; which++) {
        const float* W  = which ? Wv2 : Wk2;
        const float* bi = which ? bv2 : bk2;
        const float* g  = which ? gv : gk;
        const float* bb = which ? bv : bk;
        float a = bi[d];
#pragma unroll
        for (int j = 0; j < 64; j++) a += xs[j] * W[j * HD + d];
        float s1 = a, s2 = a * a;
#pragma unroll
        for (int o = 32; o > 0; o >>= 1) {
            s1 += __shfl_xor(s1, o);
            s2 += __shfl_xor(s2, o);
        }
        float mean = s1 * (1.f / 64.f);
        float var  = s2 * (1.f / 64.f) - mean * mean;
        float y = (a - mean) * rsqrtf(var + 1e-5f) * g[d] + bb[d];
        if (which == 0) k2b[(size_t)row * HD + d] = (bf16_t)y;
        else            v2tb[(size_t)bh * (HD * SLEN) + d * SLEN + s] = (bf16_t)y;
    }
}

// ------------------------------------------------------------------
// Main attention, MFMA flash. Block = (b,h, 64-q tile), 4 waves.
// 33 key tiles: tile 0 = summary keys (no rel bias), 1..32 = reg keys.
// Writes bf16 attn_out [r][b][E].
// ------------------------------------------------------------------
__global__ __launch_bounds__(256) void reg_attn_mfma(
    const bf16_t* __restrict__ Qb,   // [bh][r][d]
    const bf16_t* __restrict__ Kb,   // [bh][r][d]
    const bf16_t* __restrict__ Vtb,  // [bh][d][r]
    const bf16_t* __restrict__ K2b,  // [bh][s][d]
    const bf16_t* __restrict__ V2tb, // [bh][d][s]
    const float*  __restrict__ r0,   // [h][z][d]
    const int*    __restrict__ rel_idx,
    bf16_t* __restrict__ attn_out)   // [r][b][E] bf16
{
    const int bid = blockIdx.x;
    const int bh = (bid & 7) * 4 + ((bid >> 3) & 3);
    const int qt = bid >> 5;
    const int b = bh >> 4, h = bh & 15;
    const int q0 = qt * 64;

    const int t = threadIdx.x;
    const int wave = t >> 6, lane = t & 63;
    const int quad = lane >> 4, l15 = lane & 15;

    __shared__ __align__(16) bf16_t Ks[64 * LDK];
    __shared__ __align__(16) bf16_t Vs[64 * LDK];
    __shared__ __align__(16) bf16_t Ps[64 * LDK];
    __shared__ __align__(16) bf16_t qrs[64 * 64];

    const bf16_t* Qrow = Qb + (((size_t)bh * RLEN) + q0 + wave * 16 + l15) * HD;
    bf16x8 qf0 = *(const bf16x8*)(Qrow + quad * 8);
    bf16x8 qf1 = *(const bf16x8*)(Qrow + 32 + quad * 8);

#pragma unroll
    for (int nt = 0; nt < 4; nt++) {
        f32x4 qa = {0.f, 0.f, 0.f, 0.f};
        const float* rp = r0 + ((size_t)h * NZ + l15 + 16 * nt) * HD + quad * 8;
        float4 a0 = *(const float4*)(rp);
        float4 a1 = *(const float4*)(rp + 4);
        bf16x8 bf;
        bf[0] = (bf16_t)a0.x; bf[1] = (bf16_t)a0.y; bf[2] = (bf16_t)a0.z; bf[3] = (bf16_t)a0.w;
        bf[4] = (bf16_t)a1.x; bf[5] = (bf16_t)a1.y; bf[6] = (bf16_t)a1.z; bf[7] = (bf16_t)a1.w;
        qa = mfma16(qf0, bf, qa);
        float4 b0 = *(const float4*)(rp + 32);
        float4 b1 = *(const float4*)(rp + 36);
        bf[0] = (bf16_t)b0.x; bf[1] = (bf16_t)b0.y; bf[2] = (bf16_t)b0.z; bf[3] = (bf16_t)b0.w;
        bf[4] = (bf16_t)b1.x; bf[5] = (bf16_t)b1.y; bf[6] = (bf16_t)b1.z; bf[7] = (bf16_t)b1.w;
        qa = mfma16(qf1, bf, qa);
#pragma unroll
        for (int reg = 0; reg < 4; reg++)
            qrs[(wave * 16 + quad * 4 + reg) * 64 + l15 + 16 * nt] = (bf16_t)qa[reg];
    }

    f32x4 O[4];
    float m_i[4], l_i[4];
#pragma unroll
    for (int nt = 0; nt < 4; nt++) O[nt] = (f32x4){0.f, 0.f, 0.f, 0.f};
#pragma unroll
    for (int r = 0; r < 4; r++) { m_i[r] = -1e30f; l_i[r] = 0.f; }

    const int srow = t >> 2;
    const int scol = (t & 3) * 16;

    for (int tile = 0; tile < 33; tile++) {
        const bf16_t* Kt; const bf16_t* Vt;
        size_t vstr; int kk0 = 0;
        if (tile == 0) {
            Kt = K2b + (size_t)bh * (SLEN * HD);
            Vt = V2tb + (size_t)bh * (HD * SLEN);
            vstr = SLEN;
        } else {
            kk0 = (tile - 1) * 64;
            Kt = Kb + ((size_t)bh * RLEN + kk0) * HD;
            Vt = Vtb + (size_t)bh * HD * RLEN + kk0;
            vstr = RLEN;
        }
        {
            const bf16x8* ks = (const bf16x8*)(Kt + (size_t)srow * HD + scol);
            bf16x8 a0 = ks[0], a1 = ks[1];
            const bf16x8* vs = (const bf16x8*)(Vt + (size_t)srow * vstr + scol);
            bf16x8 v0 = vs[0], v1 = vs[1];
            *(bf16x8*)(Ks + srow * LDK + scol)     = a0;
            *(bf16x8*)(Ks + srow * LDK + scol + 8) = a1;
            *(bf16x8*)(Vs + srow * LDK + scol)     = v0;
            *(bf16x8*)(Vs + srow * LDK + scol + 8) = v1;
        }
        __syncthreads();

        f32x4 S[4];
#pragma unroll
        for (int nt = 0; nt < 4; nt++) {
            f32x4 acc = {0.f, 0.f, 0.f, 0.f};
            bf16x8 kf0 = *(const bf16x8*)(Ks + (l15 + 16 * nt) * LDK + quad * 8);
            bf16x8 kf1 = *(const bf16x8*)(Ks + (l15 + 16 * nt) * LDK + 32 + quad * 8);
            acc = mfma16(qf0, kf0, acc);
            acc = mfma16(qf1, kf1, acc);
            S[nt] = acc;
        }

        if (tile > 0) {
            const int* rrow = rel_idx + ((size_t)b * KTOT + SLEN + q0 + wave * 16 + quad * 4) * RLEN
                              + kk0 + l15;
#pragma unroll
            for (int reg = 0; reg < 4; reg++) {
                const int* rp = rrow + (size_t)reg * RLEN;
                int qlocal = wave * 16 + quad * 4 + reg;
#pragma unroll
                for (int nt = 0; nt < 4; nt++) {
                    int idx = rp[16 * nt];
                    S[nt][reg] += (float)qrs[qlocal * 64 + idx];
                }
            }
        }

        float tmax[4];
#pragma unroll
        for (int reg = 0; reg < 4; reg++) {
            float v = fmaxf(fmaxf(S[0][reg], S[1][reg]), fmaxf(S[2][reg], S[3][reg]));
#pragma unroll
            for (int o = 8; o > 0; o >>= 1) v = fmaxf(v, __shfl_xor(v, o));
            tmax[reg] = v;
        }
        float alpha[4], psum[4];
#pragma unroll
        for (int reg = 0; reg < 4; reg++) {
            float mn = fmaxf(m_i[reg], tmax[reg]);
            alpha[reg] = __expf(m_i[reg] - mn);
            m_i[reg] = mn;
            psum[reg] = 0.f;
        }
#pragma unroll
        for (int nt = 0; nt < 4; nt++)
#pragma unroll
            for (int reg = 0; reg < 4; reg++) {
                float p = __expf(S[nt][reg] - m_i[reg]);
                S[nt][reg] = p;
                psum[reg] += p;
            }
#pragma unroll
        for (int reg = 0; reg < 4; reg++) {
#pragma unroll
            for (int o = 8; o > 0; o >>= 1) psum[reg] += __shfl_xor(psum[reg], o);
            l_i[reg] = l_i[reg] * alpha[reg] + psum[reg];
        }
#pragma unroll
        for (int nt = 0; nt < 4; nt++) {
            O[nt][0] *= alpha[0]; O[nt][1] *= alpha[1];
            O[nt][2] *= alpha[2]; O[nt][3] *= alpha[3];
        }

#pragma unroll
        for (int nt = 0; nt < 4; nt++)
#pragma unroll
            for (int reg = 0; reg < 4; reg++)
                Ps[(wave * 16 + quad * 4 + reg) * LDK + l15 + 16 * nt] = (bf16_t)S[nt][reg];

        bf16x8 pf0 = *(const bf16x8*)(Ps + (wave * 16 + l15) * LDK + quad * 8);
        bf16x8 pf1 = *(const bf16x8*)(Ps + (wave * 16 + l15) * LDK + 32 + quad * 8);
#pragma unroll
        for (int nt = 0; nt < 4; nt++) {
            bf16x8 vf0 = *(const bf16x8*)(Vs + (l15 + 16 * nt) * LDK + quad * 8);
            bf16x8 vf1 = *(const bf16x8*)(Vs + (l15 + 16 * nt) * LDK + 32 + quad * 8);
            O[nt] = mfma16(pf0, vf0, O[nt]);
            O[nt] = mfma16(pf1, vf1, O[nt]);
        }
        __syncthreads();
    }

    float linv[4];
#pragma unroll
    for (int reg = 0; reg < 4; reg++) linv[reg] = 1.0f / l_i[reg];
#pragma unroll
    for (int nt = 0; nt < 4; nt++)
#pragma unroll
        for (int reg = 0; reg < 4; reg++) {
            int q = q0 + wave * 16 + quad * 4 + reg;
            attn_out[((size_t)q * BSZ + b) * ED + h * HD + l15 + 16 * nt] =
                (bf16_t)(O[nt][reg] * linv[reg]);
        }
}

// ------------------------------------------------------------------
extern "C" void kernel_launch(void* const* d_in, const int* in_sizes, int n_in,
                              void* d_out, int out_size, void* d_ws, size_t ws_size,
                              hipStream_t stream)
{
    const float* reg_x    = (const float*)d_in[0];
    const int*   sum_ids  = (const int*)d_in[1];
    const int*   rel_idx  = (const int*)d_in[2];
    const float* emb_sum  = (const float*)d_in[5];
    const float* rel_emb0 = (const float*)d_in[6];
    const float* Wq = (const float*)d_in[7];
    const float* bq = (const float*)d_in[8];
    const float* Wk = (const float*)d_in[9];
    const float* bk = (const float*)d_in[10];
    const float* Wv = (const float*)d_in[11];
    const float* bv = (const float*)d_in[12];
    const float* Wr0 = (const float*)d_in[13];
    const float* br0 = (const float*)d_in[14];
    const float* Wk2 = (const float*)d_in[15];
    const float* bk2 = (const float*)d_in[16];
    const float* Wv2 = (const float*)d_in[17];
    const float* bv2 = (const float*)d_in[18];
    const float* Wo  = (const float*)d_in[19];
    const float* bo  = (const float*)d_in[20];
    const float* ln_k_g  = (const float*)d_in[21];
    const float* ln_k_b  = (const float*)d_in[22];
    const float* ln_v_g  = (const float*)d_in[23];
    const float* ln_v_b  = (const float*)d_in[24];
    const float* ln_k2_g = (const float*)d_in[25];
    const float* ln_k2_b = (const float*)d_in[26];
    const float* ln_v2_g = (const float*)d_in[27];
    const float* ln_v2_b = (const float*)d_in[28];

    const size_t QKV = (size_t)BSZ * NH * RLEN * HD;   // 4,194,304
    const size_t SUM = (size_t)BSZ * NH * SLEN * HD;   // 131,072

    float* ws  = (float*)d_ws;
    float* k   = ws;                    // fp32 K (pre-LN); later aliased by aob
    float* v   = k + QKV;               // fp32 V (pre-LN / post-LN)
    float* r0  = v + QKV;               // [h][z][d]
    float* sx2 = r0 + (size_t)NH * NZ * HD;

    bf16_t* xb   = (bf16_t*)(sx2 + SUM);
    bf16_t* qb   = xb + QKV;
    bf16_t* kb   = qb + QKV;
    bf16_t* vtb  = kb + QKV;
    bf16_t* sqb  = vtb + QKV;
    bf16_t* k2b  = sqb + SUM;
    bf16_t* v2tb = k2b + SUM;
    bf16_t* wqt  = v2tb + SUM;
    bf16_t* wkt  = wqt + (size_t)ED * ED;
    bf16_t* wvt  = wkt + (size_t)ED * ED;
    bf16_t* wot  = wvt + (size_t)ED * ED;
    bf16_t* wr0t = wot + (size_t)ED * ED;
    bf16_t* re0b = wr0t + (size_t)ED * NZ;
    bf16_t* aob  = (bf16_t*)k;          // alias: fp32 K dead after cvt to kb

    const int M = RLEN * BSZ;   // 4096
    dim3 gProj(ED / 128, M / 64);       // (8, 64)
    dim3 gWt(ED / 64, ED / 64);         // 16x16

    // --- precision conversions ---
    cvt_bf16<<<(int)(QKV / 1024), 256, 0, stream>>>(reg_x, xb, (int)QKV);
    transpose_cvt2<<<gWt, 256, 0, stream>>>(Wq, wqt, ED, ED);
    transpose_cvt2<<<gWt, 256, 0, stream>>>(Wk, wkt, ED, ED);
    transpose_cvt2<<<gWt, 256, 0, stream>>>(Wv, wvt, ED, ED);
    transpose_cvt2<<<gWt, 256, 0, stream>>>(Wo, wot, ED, ED);
    transpose_cvt2<<<dim3(ED / 64, 1), 256, 0, stream>>>(Wr0, wr0t, NZ, ED);
    cvt_bf16<<<4, 256, 0, stream>>>(rel_emb0, re0b, NZ * NZ);

    // --- projections (MFMA) ---
    gemm_mfma<<<gProj, 256, 0, stream>>>(xb, wqt, bq, qb, M, ED, ED, 0.125f, 1, 1, BSZ, RLEN);
    gemm_mfma<<<gProj, 256, 0, stream>>>(xb, wkt, bk, k,  M, ED, ED, 1.f,    1, 0, BSZ, RLEN);
    gemm_mfma<<<gProj, 256, 0, stream>>>(xb, wvt, bv, v,  M, ED, ED, 1.f,    1, 0, BSZ, RLEN);

    ln_heads<<<(BSZ * NH * RLEN) / 4, 256, 0, stream>>>(k, ln_k_g, ln_k_b, kb, 1);
    ln_heads<<<(BSZ * NH * RLEN) / 4, 256, 0, stream>>>(v, ln_v_g, ln_v_b, nullptr, 0);
    transpose_cvt<<<dim3(RLEN / 64, BSZ * NH), 256, 0, stream>>>(v, vtb, RLEN);

    // r0 = rel_emb0 @ Wr0 -> fp32 [h][z][d]
    gemm_mfma<<<dim3(ED / 128, 1), 256, 0, stream>>>(re0b, wr0t, br0, r0, NZ, NZ, ED, 1.f, 1, 0, 1, NZ);

    sumq_gather<<<SLEN * BSZ, 256, 0, stream>>>(emb_sum, sum_ids, sqb);

    sum_attn_mfma<<<BSZ * NH, 256, 0, stream>>>(sqb, kb, vtb, r0, rel_idx, sx2);

    k2v2<<<BSZ * NH * SLEN, 64, 0, stream>>>(sx2, Wk2, bk2, Wv2, bv2,
                                             ln_k2_g, ln_k2_b, ln_v2_g, ln_v2_b, k2b, v2tb);

    reg_attn_mfma<<<BSZ * NH * (RLEN / 64), 256, 0, stream>>>(qb, kb, vtb, k2b, v2tb,
                                                              r0, rel_idx, aob);

    // final projection -> d_out fp32 (R,B,E)
    gemm_mfma<<<gProj, 256, 0, stream>>>(aob, wot, bo, (float*)d_out, M, ED, ED, 1.f, 0, 0, BSZ, RLEN);
}

// Round 4
// 424.663 us; speedup vs baseline: 7.7711x; 1.7017x over previous
//
#include <hip/hip_runtime.h>
#include <cstdint>
#include <cstddef>

#define NH   16
#define HD   64
#define RLEN 2048
#define BSZ  2
#define SLEN 64
#define NZ   64
#define ED   1024
#define KTOT 2112   // SLEN + RLEN
#define LDK  72     // padded LDS row stride (bf16) for attention tiles
#define NSPLIT 8    // sum_attn key splits

typedef __bf16 bf16_t;
typedef bf16_t bf16x8 __attribute__((ext_vector_type(8)));
typedef bf16_t bf16x4 __attribute__((ext_vector_type(4)));
typedef float  f32x4  __attribute__((ext_vector_type(4)));

__device__ __forceinline__ f32x4 mfma16(bf16x8 a, bf16x8 b, f32x4 c) {
    return __builtin_amdgcn_mfma_f32_16x16x32_bf16(a, b, c, 0, 0, 0);
}

// ------------------------------------------------------------------
// 64x128 bf16 MFMA GEMM (kept for small r0 gemm, M=64).
// A [M][K], Bt [N][K], mode1 head layout out.
// ------------------------------------------------------------------
__global__ __launch_bounds__(256) void gemm_mfma(
    const bf16_t* __restrict__ A, const bf16_t* __restrict__ Bt,
    const float* __restrict__ bias, void* __restrict__ outp,
    int M, int K, int N, float scale, int mode, int obf, int Bsz, int Rr)
{
    constexpr int LDA = 40;
    __shared__ __align__(16) bf16_t As[64 * LDA];
    __shared__ __align__(16) bf16_t Bs[128 * LDA];

    const int t = threadIdx.x;
    const int wave = t >> 6, lane = t & 63;
    const int quad = lane >> 4, l15 = lane & 15;
    const int wrow = wave >> 1, wcol = wave & 1;
    const int m0 = blockIdx.y * 64, n0 = blockIdx.x * 128;

    f32x4 acc[2][4];
#pragma unroll
    for (int i = 0; i < 2; i++)
#pragma unroll
        for (int j = 0; j < 4; j++) acc[i][j] = (f32x4){0.f, 0.f, 0.f, 0.f};

    const int srow = t >> 2, sseg = (t & 3) * 8;

    for (int k0 = 0; k0 < K; k0 += 32) {
        bf16x8 av  = *(const bf16x8*)(A  + (size_t)(m0 + srow) * K + k0 + sseg);
        bf16x8 bv0 = *(const bf16x8*)(Bt + (size_t)(n0 + srow) * K + k0 + sseg);
        bf16x8 bv1 = *(const bf16x8*)(Bt + (size_t)(n0 + 64 + srow) * K + k0 + sseg);
        __syncthreads();
        *(bf16x8*)(As + srow * LDA + sseg)        = av;
        *(bf16x8*)(Bs + srow * LDA + sseg)        = bv0;
        *(bf16x8*)(Bs + (64 + srow) * LDA + sseg) = bv1;
        __syncthreads();

        bf16x8 af[2], bf[4];
#pragma unroll
        for (int mt = 0; mt < 2; mt++)
            af[mt] = *(const bf16x8*)(As + (wrow * 32 + mt * 16 + l15) * LDA + quad * 8);
#pragma unroll
        for (int nt = 0; nt < 4; nt++)
            bf[nt] = *(const bf16x8*)(Bs + (wcol * 64 + nt * 16 + l15) * LDA + quad * 8);
#pragma unroll
        for (int mt = 0; mt < 2; mt++)
#pragma unroll
            for (int nt = 0; nt < 4; nt++)
                acc[mt][nt] = mfma16(af[mt], bf[nt], acc[mt][nt]);
    }

    float* outf = (float*)outp;
    bf16_t* outb = (bf16_t*)outp;
#pragma unroll
    for (int mt = 0; mt < 2; mt++)
#pragma unroll
        for (int nt = 0; nt < 4; nt++)
#pragma unroll
            for (int reg = 0; reg < 4; reg++) {
                int m = m0 + wrow * 32 + mt * 16 + quad * 4 + reg;
                int n = n0 + wcol * 64 + nt * 16 + l15;
                if (m >= M) continue;
                float c = (acc[mt][nt][reg] + bias[n]) * scale;
                size_t off;
                if (mode == 0) off = (size_t)m * N + n;
                else {
                    int h = n >> 6, d = n & 63;
                    int r = m / Bsz, bb = m % Bsz;
                    off = (((size_t)bb * NH + h) * Rr + r) * HD + d;
                }
                if (obf) outb[off] = (bf16_t)c; else outf[off] = c;
            }
}

// ------------------------------------------------------------------
// 128x128 bf16 MFMA GEMM, generic epilogue: out fp32 [M][N] = A@B + bias.
// 4 waves, each 32(M)x128(N). M,N mult of 128, K mult of 32.
// ------------------------------------------------------------------
__global__ __launch_bounds__(256) void gemm_big(
    const bf16_t* __restrict__ A, const bf16_t* __restrict__ Bt,
    const float* __restrict__ bias, float* __restrict__ out,
    int M, int K, int N)
{
    constexpr int LDA = 40;
    __shared__ __align__(16) bf16_t As[128 * LDA];
    __shared__ __align__(16) bf16_t Bs[128 * LDA];

    const int t = threadIdx.x;
    const int wave = t >> 6, lane = t & 63;
    const int quad = lane >> 4, l15 = lane & 15;
    const int m0 = blockIdx.y * 128, n0 = blockIdx.x * 128;

    f32x4 acc[2][8];
#pragma unroll
    for (int i = 0; i < 2; i++)
#pragma unroll
        for (int j = 0; j < 8; j++) acc[i][j] = (f32x4){0.f, 0.f, 0.f, 0.f};

    const int srow = t >> 2, sseg = (t & 3) * 8;

    for (int k0 = 0; k0 < K; k0 += 32) {
        bf16x8 a0 = *(const bf16x8*)(A + (size_t)(m0 + srow) * K + k0 + sseg);
        bf16x8 a1 = *(const bf16x8*)(A + (size_t)(m0 + 64 + srow) * K + k0 + sseg);
        bf16x8 b0 = *(const bf16x8*)(Bt + (size_t)(n0 + srow) * K + k0 + sseg);
        bf16x8 b1 = *(const bf16x8*)(Bt + (size_t)(n0 + 64 + srow) * K + k0 + sseg);
        __syncthreads();
        *(bf16x8*)(As + srow * LDA + sseg)        = a0;
        *(bf16x8*)(As + (64 + srow) * LDA + sseg) = a1;
        *(bf16x8*)(Bs + srow * LDA + sseg)        = b0;
        *(bf16x8*)(Bs + (64 + srow) * LDA + sseg) = b1;
        __syncthreads();

        bf16x8 af[2], bf[8];
#pragma unroll
        for (int mt = 0; mt < 2; mt++)
            af[mt] = *(const bf16x8*)(As + (wave * 32 + mt * 16 + l15) * LDA + quad * 8);
#pragma unroll
        for (int nt = 0; nt < 8; nt++)
            bf[nt] = *(const bf16x8*)(Bs + (nt * 16 + l15) * LDA + quad * 8);
#pragma unroll
        for (int mt = 0; mt < 2; mt++)
#pragma unroll
            for (int nt = 0; nt < 8; nt++)
                acc[mt][nt] = mfma16(af[mt], bf[nt], acc[mt][nt]);
    }

#pragma unroll
    for (int mt = 0; mt < 2; mt++)
#pragma unroll
        for (int nt = 0; nt < 8; nt++)
#pragma unroll
            for (int reg = 0; reg < 4; reg++) {
                int m = m0 + wave * 32 + mt * 16 + quad * 4 + reg;
                int n = n0 + nt * 16 + l15;
                out[(size_t)m * N + n] = acc[mt][nt][reg] + bias[n];
            }
}

// ------------------------------------------------------------------
// Fused QKV projection: A=xb [4096][1024], Bt = [wqt|wkt|wvt] [3072][1024].
// seg0 -> qb bf16 head layout *0.125; seg1 -> k fp32 head; seg2 -> v fp32 head.
// ------------------------------------------------------------------
__global__ __launch_bounds__(256) void gemm_qkv(
    const bf16_t* __restrict__ A, const bf16_t* __restrict__ Bt,
    const float* __restrict__ bq, const float* __restrict__ bk,
    const float* __restrict__ bv,
    bf16_t* __restrict__ qb, float* __restrict__ kf, float* __restrict__ vf)
{
    constexpr int K = ED, N = 3 * ED;
    constexpr int LDA = 40;
    __shared__ __align__(16) bf16_t As[128 * LDA];
    __shared__ __align__(16) bf16_t Bs[128 * LDA];

    const int t = threadIdx.x;
    const int wave = t >> 6, lane = t & 63;
    const int quad = lane >> 4, l15 = lane & 15;
    const int m0 = blockIdx.y * 128, n0 = blockIdx.x * 128;

    f32x4 acc[2][8];
#pragma unroll
    for (int i = 0; i < 2; i++)
#pragma unroll
        for (int j = 0; j < 8; j++) acc[i][j] = (f32x4){0.f, 0.f, 0.f, 0.f};

    const int srow = t >> 2, sseg = (t & 3) * 8;

    for (int k0 = 0; k0 < K; k0 += 32) {
        bf16x8 a0 = *(const bf16x8*)(A + (size_t)(m0 + srow) * K + k0 + sseg);
        bf16x8 a1 = *(const bf16x8*)(A + (size_t)(m0 + 64 + srow) * K + k0 + sseg);
        bf16x8 b0 = *(const bf16x8*)(Bt + (size_t)(n0 + srow) * K + k0 + sseg);
        bf16x8 b1 = *(const bf16x8*)(Bt + (size_t)(n0 + 64 + srow) * K + k0 + sseg);
        __syncthreads();
        *(bf16x8*)(As + srow * LDA + sseg)        = a0;
        *(bf16x8*)(As + (64 + srow) * LDA + sseg) = a1;
        *(bf16x8*)(Bs + srow * LDA + sseg)        = b0;
        *(bf16x8*)(Bs + (64 + srow) * LDA + sseg) = b1;
        __syncthreads();

        bf16x8 af[2], bf[8];
#pragma unroll
        for (int mt = 0; mt < 2; mt++)
            af[mt] = *(const bf16x8*)(As + (wave * 32 + mt * 16 + l15) * LDA + quad * 8);
#pragma unroll
        for (int nt = 0; nt < 8; nt++)
            bf[nt] = *(const bf16x8*)(Bs + (nt * 16 + l15) * LDA + quad * 8);
#pragma unroll
        for (int mt = 0; mt < 2; mt++)
#pragma unroll
            for (int nt = 0; nt < 8; nt++)
                acc[mt][nt] = mfma16(af[mt], bf[nt], acc[mt][nt]);
    }

    const int seg = n0 >> 10;   // block-uniform: 0=Q, 1=K, 2=V
    const float* bias = (seg == 0) ? bq : (seg == 1) ? bk : bv;
#pragma unroll
    for (int mt = 0; mt < 2; mt++)
#pragma unroll
        for (int nt = 0; nt < 8; nt++)
#pragma unroll
            for (int reg = 0; reg < 4; reg++) {
                int m = m0 + wave * 32 + mt * 16 + quad * 4 + reg;
                int nl = ((n0 + nt * 16 + l15) & 1023);
                float c = acc[mt][nt][reg] + bias[nl];
                int h = nl >> 6, d = nl & 63;
                int r = m >> 1, bb = m & 1;
                size_t off = (((size_t)bb * NH + h) * RLEN + r) * HD + d;
                if (seg == 0)      qb[off] = (bf16_t)(c * 0.125f);
                else if (seg == 1) kf[off] = c;
                else               vf[off] = c;
            }
}

// ------------------------------------------------------------------
// LayerNorm over trailing 64, one wave per row (used for K -> bf16).
// ------------------------------------------------------------------
__global__ __launch_bounds__(256) void ln_heads(
    float* __restrict__ x, const float* __restrict__ g, const float* __restrict__ b,
    bf16_t* __restrict__ outb, int to_bf16)
{
    int row  = blockIdx.x * 4 + (threadIdx.x >> 6);
    int lane = threadIdx.x & 63;
    float v = x[(size_t)row * HD + lane];
    float s1 = v, s2 = v * v;
#pragma unroll
    for (int o = 32; o > 0; o >>= 1) {
        s1 += __shfl_xor(s1, o);
        s2 += __shfl_xor(s2, o);
    }
    float mean = s1 * (1.f / 64.f);
    float var  = s2 * (1.f / 64.f) - mean * mean;
    float y = (v - mean) * rsqrtf(var + 1e-5f) * g[lane] + b[lane];
    if (to_bf16) outb[(size_t)row * HD + lane] = (bf16_t)y;
    else         x[(size_t)row * HD + lane] = y;
}

// ------------------------------------------------------------------
// Fused V-LN + transpose: v fp32 [bh][r][d] -> vtb bf16 [bh][d][r].
// grid (RLEN/64, BSZ*NH), 256 threads (4 waves x 16 rows).
// ------------------------------------------------------------------
__global__ __launch_bounds__(256) void lnv_t(
    const float* __restrict__ v, const float* __restrict__ g,
    const float* __restrict__ b, bf16_t* __restrict__ vtb)
{
    __shared__ float tile[64][65];
    const int bh = blockIdx.y, r0 = blockIdx.x * 64;
    const int t = threadIdx.x;
    const int wave = t >> 6, lane = t & 63;

#pragma unroll
    for (int i = 0; i < 16; i++) {
        int rl = wave * 16 + i;
        float x = v[((size_t)bh * RLEN + r0 + rl) * HD + lane];
        float s1 = x, s2 = x * x;
#pragma unroll
        for (int o = 32; o > 0; o >>= 1) {
            s1 += __shfl_xor(s1, o);
            s2 += __shfl_xor(s2, o);
        }
        float mean = s1 * (1.f / 64.f);
        float var  = s2 * (1.f / 64.f) - mean * mean;
        tile[rl][lane] = (x - mean) * rsqrtf(var + 1e-5f) * g[lane] + b[lane];
    }
    __syncthreads();
    bf16_t* dst = vtb + (size_t)bh * HD * RLEN + r0;
    int d = t >> 2, rs = (t & 3) * 16;
    bf16x8 o0, o1;
#pragma unroll
    for (int j = 0; j < 8; j++) {
        o0[j] = (bf16_t)tile[rs + j][d];
        o1[j] = (bf16_t)tile[rs + 8 + j][d];
    }
    *(bf16x8*)(dst + (size_t)d * RLEN + rs) = o0;
    *(bf16x8*)(dst + (size_t)d * RLEN + rs + 8) = o1;
}

// ------------------------------------------------------------------
// fp32 -> bf16, 4 elems/thread.
// ------------------------------------------------------------------
__global__ __launch_bounds__(256) void cvt_bf16(
    const float* __restrict__ src, bf16_t* __restrict__ dst, int n)
{
    int i = (blockIdx.x * 256 + threadIdx.x) * 4;
    if (i < n) {
        float4 v = *(const float4*)(src + i);
        bf16x4 o;
        o[0] = (bf16_t)v.x; o[1] = (bf16_t)v.y; o[2] = (bf16_t)v.z; o[3] = (bf16_t)v.w;
        *(bf16x4*)(dst + i) = o;
    }
}

// ------------------------------------------------------------------
// Batched weight transpose+cvt: 4x (1024x1024) + 1x (64x1024).
// src [R][C] -> dst [C][R] bf16. grid 1040 blocks.
// ------------------------------------------------------------------
__global__ __launch_bounds__(256) void wt_batch(
    const float* __restrict__ Wq, const float* __restrict__ Wk,
    const float* __restrict__ Wv, const float* __restrict__ Wo,
    const float* __restrict__ Wr0,
    bf16_t* __restrict__ wqt, bf16_t* __restrict__ wkt,
    bf16_t* __restrict__ wvt, bf16_t* __restrict__ wot,
    bf16_t* __restrict__ wr0t)
{
    __shared__ float tile[64][65];
    const int bid = blockIdx.x;
    const float* src; bf16_t* dst; int R, C, r0, c0;
    if (bid < 1024) {
        int sel = bid >> 8, local = bid & 255;
        src = (sel == 0) ? Wq : (sel == 1) ? Wk : (sel == 2) ? Wv : Wo;
        dst = (sel == 0) ? wqt : (sel == 1) ? wkt : (sel == 2) ? wvt : wot;
        R = ED; C = ED; r0 = (local >> 4) * 64; c0 = (local & 15) * 64;
    } else {
        src = Wr0; dst = wr0t; R = NZ; C = ED; r0 = 0; c0 = (bid - 1024) * 64;
    }
    const int t = threadIdx.x;
#pragma unroll
    for (int i = 0; i < 4; i++) {
        int idx = t + i * 256;
        int r = idx >> 4, c = (idx & 15) * 4;
        float4 vv = *(const float4*)(src + (size_t)(r0 + r) * C + c0 + c);
        tile[r][c] = vv.x; tile[r][c + 1] = vv.y; tile[r][c + 2] = vv.z; tile[r][c + 3] = vv.w;
    }
    __syncthreads();
    int cc = t >> 2, rs = (t & 3) * 16;
    bf16x8 o0, o1;
#pragma unroll
    for (int j = 0; j < 8; j++) {
        o0[j] = (bf16_t)tile[rs + j][cc];
        o1[j] = (bf16_t)tile[rs + 8 + j][cc];
    }
    *(bf16x8*)(dst + (size_t)(c0 + cc) * R + r0 + rs) = o0;
    *(bf16x8*)(dst + (size_t)(c0 + cc) * R + r0 + rs + 8) = o1;
}

// ------------------------------------------------------------------
// sum_q gather -> bf16, pre-scaled.
// ------------------------------------------------------------------
__global__ __launch_bounds__(256) void sumq_gather(
    const float* __restrict__ emb, const int* __restrict__ ids,
    bf16_t* __restrict__ sum_q)
{
    int sb = blockIdx.x;
    int s = sb >> 1, b = sb & 1;
    int id = ids[b * SLEN + s];
    const float* src = emb + (size_t)id * ED;
    for (int e = threadIdx.x; e < ED; e += 256) {
        int h = e >> 6, d = e & 63;
        sum_q[(((size_t)b * NH + h) * SLEN + s) * HD + d] = (bf16_t)(src[e] * 0.125f);
    }
}

// ------------------------------------------------------------------
// Summary attention, MFMA flash with split-K. grid (32 bh, NSPLIT).
// Each split handles 4 key-tiles of 64; writes unnormalized partial
// O + m + l.
// ------------------------------------------------------------------
__global__ __launch_bounds__(256) void sum_attn_split(
    const bf16_t* __restrict__ Qb,   // sum_q [bh][s][d]
    const bf16_t* __restrict__ Kb,   // [bh][r][d]
    const bf16_t* __restrict__ Vtb,  // [bh][d][r]
    const float*  __restrict__ r0,   // [h][z][d]
    const int*    __restrict__ rel_idx,
    float* __restrict__ po, float* __restrict__ pm, float* __restrict__ pl)
{
    const int bh = blockIdx.x;
    const int split = blockIdx.y;
    const int b = bh >> 4, h = bh & 15;
    const int t = threadIdx.x;
    const int wave = t >> 6, lane = t & 63;
    const int quad = lane >> 4, l15 = lane & 15;

    __shared__ __align__(16) bf16_t Ks[64 * LDK];
    __shared__ __align__(16) bf16_t Vs[64 * LDK];
    __shared__ __align__(16) bf16_t Ps[64 * LDK];
    __shared__ __align__(16) bf16_t qrs[64 * 64];

    const bf16_t* Qrow = Qb + ((size_t)bh * SLEN + wave * 16 + l15) * HD;
    bf16x8 qf0 = *(const bf16x8*)(Qrow + quad * 8);
    bf16x8 qf1 = *(const bf16x8*)(Qrow + 32 + quad * 8);

#pragma unroll
    for (int nt = 0; nt < 4; nt++) {
        f32x4 qa = {0.f, 0.f, 0.f, 0.f};
        const float* rp = r0 + ((size_t)h * NZ + l15 + 16 * nt) * HD + quad * 8;
        float4 a0 = *(const float4*)(rp);
        float4 a1 = *(const float4*)(rp + 4);
        bf16x8 bf;
        bf[0] = (bf16_t)a0.x; bf[1] = (bf16_t)a0.y; bf[2] = (bf16_t)a0.z; bf[3] = (bf16_t)a0.w;
        bf[4] = (bf16_t)a1.x; bf[5] = (bf16_t)a1.y; bf[6] = (bf16_t)a1.z; bf[7] = (bf16_t)a1.w;
        qa = mfma16(qf0, bf, qa);
        float4 b0 = *(const float4*)(rp + 32);
        float4 b1 = *(const float4*)(rp + 36);
        bf[0] = (bf16_t)b0.x; bf[1] = (bf16_t)b0.y; bf[2] = (bf16_t)b0.z; bf[3] = (bf16_t)b0.w;
        bf[4] = (bf16_t)b1.x; bf[5] = (bf16_t)b1.y; bf[6] = (bf16_t)b1.z; bf[7] = (bf16_t)b1.w;
        qa = mfma16(qf1, bf, qa);
#pragma unroll
        for (int reg = 0; reg < 4; reg++)
            qrs[(wave * 16 + quad * 4 + reg) * 64 + l15 + 16 * nt] = (bf16_t)qa[reg];
    }

    f32x4 O[4];
    float m_i[4], l_i[4];
#pragma unroll
    for (int nt = 0; nt < 4; nt++) O[nt] = (f32x4){0.f, 0.f, 0.f, 0.f};
#pragma unroll
    for (int r = 0; r < 4; r++) { m_i[r] = -1e30f; l_i[r] = 0.f; }

    const int srow = t >> 2;
    const int scol = (t & 3) * 16;

    for (int i = 0; i < 32 / NSPLIT; i++) {
        const int kk0 = (split * (32 / NSPLIT) + i) * 64;
        const bf16_t* Kt = Kb + ((size_t)bh * RLEN + kk0) * HD;
        const bf16_t* Vt = Vtb + (size_t)bh * HD * RLEN + kk0;
        {
            const bf16x8* ks = (const bf16x8*)(Kt + (size_t)srow * HD + scol);
            bf16x8 a0 = ks[0], a1 = ks[1];
            const bf16x8* vs = (const bf16x8*)(Vt + (size_t)srow * RLEN + scol);
            bf16x8 v0 = vs[0], v1 = vs[1];
            *(bf16x8*)(Ks + srow * LDK + scol)     = a0;
            *(bf16x8*)(Ks + srow * LDK + scol + 8) = a1;
            *(bf16x8*)(Vs + srow * LDK + scol)     = v0;
            *(bf16x8*)(Vs + srow * LDK + scol + 8) = v1;
        }
        __syncthreads();

        f32x4 S[4];
#pragma unroll
        for (int nt = 0; nt < 4; nt++) {
            f32x4 acc = {0.f, 0.f, 0.f, 0.f};
            bf16x8 kf0 = *(const bf16x8*)(Ks + (l15 + 16 * nt) * LDK + quad * 8);
            bf16x8 kf1 = *(const bf16x8*)(Ks + (l15 + 16 * nt) * LDK + 32 + quad * 8);
            acc = mfma16(qf0, kf0, acc);
            acc = mfma16(qf1, kf1, acc);
            S[nt] = acc;
        }

        const int* rrow = rel_idx + ((size_t)b * KTOT + wave * 16 + quad * 4) * RLEN + kk0 + l15;
#pragma unroll
        for (int reg = 0; reg < 4; reg++) {
            const int* rp = rrow + (size_t)reg * RLEN;
            int qlocal = wave * 16 + quad * 4 + reg;
#pragma unroll
            for (int nt = 0; nt < 4; nt++) {
                int idx = rp[16 * nt];
                S[nt][reg] += (float)qrs[qlocal * 64 + idx];
            }
        }

        float tmax[4];
#pragma unroll
        for (int reg = 0; reg < 4; reg++) {
            float v = fmaxf(fmaxf(S[0][reg], S[1][reg]), fmaxf(S[2][reg], S[3][reg]));
#pragma unroll
            for (int o = 8; o > 0; o >>= 1) v = fmaxf(v, __shfl_xor(v, o));
            tmax[reg] = v;
        }
        float alpha[4], psum[4];
#pragma unroll
        for (int reg = 0; reg < 4; reg++) {
            float mn = fmaxf(m_i[reg], tmax[reg]);
            alpha[reg] = __expf(m_i[reg] - mn);
            m_i[reg] = mn;
            psum[reg] = 0.f;
        }
#pragma unroll
        for (int nt = 0; nt < 4; nt++)
#pragma unroll
            for (int reg = 0; reg < 4; reg++) {
                float p = __expf(S[nt][reg] - m_i[reg]);
                S[nt][reg] = p;
                psum[reg] += p;
            }
#pragma unroll
        for (int reg = 0; reg < 4; reg++) {
#pragma unroll
            for (int o = 8; o > 0; o >>= 1) psum[reg] += __shfl_xor(psum[reg], o);
            l_i[reg] = l_i[reg] * alpha[reg] + psum[reg];
        }
#pragma unroll
        for (int nt = 0; nt < 4; nt++) {
            O[nt][0] *= alpha[0]; O[nt][1] *= alpha[1];
            O[nt][2] *= alpha[2]; O[nt][3] *= alpha[3];
        }

#pragma unroll
        for (int nt = 0; nt < 4; nt++)
#pragma unroll
            for (int reg = 0; reg < 4; reg++)
                Ps[(wave * 16 + quad * 4 + reg) * LDK + l15 + 16 * nt] = (bf16_t)S[nt][reg];

        bf16x8 pf0 = *(const bf16x8*)(Ps + (wave * 16 + l15) * LDK + quad * 8);
        bf16x8 pf1 = *(const bf16x8*)(Ps + (wave * 16 + l15) * LDK + 32 + quad * 8);
#pragma unroll
        for (int nt = 0; nt < 4; nt++) {
            bf16x8 vf0 = *(const bf16x8*)(Vs + (l15 + 16 * nt) * LDK + quad * 8);
            bf16x8 vf1 = *(const bf16x8*)(Vs + (l15 + 16 * nt) * LDK + 32 + quad * 8);
            O[nt] = mfma16(pf0, vf0, O[nt]);
            O[nt] = mfma16(pf1, vf1, O[nt]);
        }
        __syncthreads();
    }

    const size_t pslot = (size_t)bh * NSPLIT + split;
#pragma unroll
    for (int nt = 0; nt < 4; nt++)
#pragma unroll
        for (int reg = 0; reg < 4; reg++) {
            int sq = wave * 16 + quad * 4 + reg;
            po[(pslot * SLEN + sq) * HD + l15 + 16 * nt] = O[nt][reg];
        }
#pragma unroll
    for (int reg = 0; reg < 4; reg++) {
        int sq = wave * 16 + quad * 4 + reg;
        if (l15 == 0) {
            pm[pslot * SLEN + sq] = m_i[reg];
            pl[pslot * SLEN + sq] = l_i[reg];
        }
    }
}

// ------------------------------------------------------------------
// Combine split partials -> sum_x2 fp32 [bh][s][d]. grid (32, 4).
// ------------------------------------------------------------------
__global__ __launch_bounds__(256) void sum_reduce(
    const float* __restrict__ po, const float* __restrict__ pm,
    const float* __restrict__ pl, float* __restrict__ sum_x2)
{
    const int bh = blockIdx.x;
    const int sg0 = blockIdx.y * 16;
    const int t = threadIdx.x;
    const int d = t & 63, si = t >> 6;
#pragma unroll
    for (int i = 0; i < 4; i++) {
        int s = sg0 + si * 4 + i;
        float M = -1e30f, mm[NSPLIT];
#pragma unroll
        for (int j = 0; j < NSPLIT; j++) {
            mm[j] = pm[((size_t)bh * NSPLIT + j) * SLEN + s];
            M = fmaxf(M, mm[j]);
        }
        float L = 0.f, acc = 0.f;
#pragma unroll
        for (int j = 0; j < NSPLIT; j++) {
            float a = __expf(mm[j] - M);
            L += pl[((size_t)bh * NSPLIT + j) * SLEN + s] * a;
            acc += po[(((size_t)bh * NSPLIT + j) * SLEN + s) * HD + d] * a;
        }
        sum_x2[((size_t)bh * SLEN + s) * HD + d] = acc / L;
    }
}

// ------------------------------------------------------------------
// sum_k2 / sum_v2: y = LN(x @ W + b); bf16 K2 [bh][s][d], V2t [bh][d][s].
// ------------------------------------------------------------------
__global__ __launch_bounds__(64) void k2v2(
    const float* __restrict__ sum_x2,
    const float* __restrict__ Wk2, const float* __restrict__ bk2,
    const float* __restrict__ Wv2, const float* __restrict__ bv2,
    const float* __restrict__ gk, const float* __restrict__ bk,
    const float* __restrict__ gv, const float* __restrict__ bv,
    bf16_t* __restrict__ k2b, bf16_t* __restrict__ v2tb)
{
    int row = blockIdx.x;              // bh*64 + s
    int d = threadIdx.x;
    int bh = row >> 6, s = row & 63;
    __shared__ float xs[64];
    xs[d] = sum_x2[(size_t)row * HD + d];
    __syncthreads();

#pragma unroll
    for (int which = 0; which < 2; which++) {
        const float* W  = which ? Wv2 : Wk2;
        const float* bi = which ? bv2 : bk2;
        const float* g  = which ? gv : gk;
        const float* bb = which ? bv : bk;
        float a = bi[d];
#pragma unroll
        for (int j = 0; j < 64; j++) a += xs[j] * W[j * HD + d];
        float s1 = a, s2 = a * a;
#pragma unroll
        for (int o = 32; o > 0; o >>= 1) {
            s1 += __shfl_xor(s1, o);
            s2 += __shfl_xor(s2, o);
        }
        float mean = s1 * (1.f / 64.f);
        float var  = s2 * (1.f / 64.f) - mean * mean;
        float y = (a - mean) * rsqrtf(var + 1e-5f) * g[d] + bb[d];
        if (which == 0) k2b[(size_t)row * HD + d] = (bf16_t)y;
        else            v2tb[(size_t)bh * (HD * SLEN) + d * SLEN + s] = (bf16_t)y;
    }
}

// ------------------------------------------------------------------
// Main attention, MFMA flash, software-pipelined: K/V staging and
// rel_idx prefetched into registers one tile ahead.
// ------------------------------------------------------------------
__global__ __launch_bounds__(256, 4) void reg_attn_mfma(
    const bf16_t* __restrict__ Qb,   // [bh][r][d]
    const bf16_t* __restrict__ Kb,   // [bh][r][d]
    const bf16_t* __restrict__ Vtb,  // [bh][d][r]
    const bf16_t* __restrict__ K2b,  // [bh][s][d]
    const bf16_t* __restrict__ V2tb, // [bh][d][s]
    const float*  __restrict__ r0,   // [h][z][d]
    const int*    __restrict__ rel_idx,
    bf16_t* __restrict__ attn_out)   // [r][b][E] bf16
{
    const int bid = blockIdx.x;
    const int bh = (bid & 7) * 4 + ((bid >> 3) & 3);
    const int qt = bid >> 5;
    const int b = bh >> 4, h = bh & 15;
    const int q0 = qt * 64;

    const int t = threadIdx.x;
    const int wave = t >> 6, lane = t & 63;
    const int quad = lane >> 4, l15 = lane & 15;

    __shared__ __align__(16) bf16_t Ks[64 * LDK];
    __shared__ __align__(16) bf16_t Vs[64 * LDK];
    __shared__ __align__(16) bf16_t Ps[64 * LDK];
    __shared__ __align__(16) bf16_t qrs[64 * 64];

    const bf16_t* Qrow = Qb + (((size_t)bh * RLEN) + q0 + wave * 16 + l15) * HD;
    bf16x8 qf0 = *(const bf16x8*)(Qrow + quad * 8);
    bf16x8 qf1 = *(const bf16x8*)(Qrow + 32 + quad * 8);

#pragma unroll
    for (int nt = 0; nt < 4; nt++) {
        f32x4 qa = {0.f, 0.f, 0.f, 0.f};
        const float* rp = r0 + ((size_t)h * NZ + l15 + 16 * nt) * HD + quad * 8;
        float4 a0 = *(const float4*)(rp);
        float4 a1 = *(const float4*)(rp + 4);
        bf16x8 bf;
        bf[0] = (bf16_t)a0.x; bf[1] = (bf16_t)a0.y; bf[2] = (bf16_t)a0.z; bf[3] = (bf16_t)a0.w;
        bf[4] = (bf16_t)a1.x; bf[5] = (bf16_t)a1.y; bf[6] = (bf16_t)a1.z; bf[7] = (bf16_t)a1.w;
        qa = mfma16(qf0, bf, qa);
        float4 b0 = *(const float4*)(rp + 32);
        float4 b1 = *(const float4*)(rp + 36);
        bf[0] = (bf16_t)b0.x; bf[1] = (bf16_t)b0.y; bf[2] = (bf16_t)b0.z; bf[3] = (bf16_t)b0.w;
        bf[4] = (bf16_t)b1.x; bf[5] = (bf16_t)b1.y; bf[6] = (bf16_t)b1.z; bf[7] = (bf16_t)b1.w;
        qa = mfma16(qf1, bf, qa);
#pragma unroll
        for (int reg = 0; reg < 4; reg++)
            qrs[(wave * 16 + quad * 4 + reg) * 64 + l15 + 16 * nt] = (bf16_t)qa[reg];
    }

    f32x4 O[4];
    float m_i[4], l_i[4];
#pragma unroll
    for (int nt = 0; nt < 4; nt++) O[nt] = (f32x4){0.f, 0.f, 0.f, 0.f};
#pragma unroll
    for (int r = 0; r < 4; r++) { m_i[r] = -1e30f; l_i[r] = 0.f; }

    const int srow = t >> 2;
    const int scol = (t & 3) * 16;
    const int* relbase = rel_idx + ((size_t)b * KTOT + SLEN + q0 + wave * 16 + quad * 4) * RLEN + l15;

    // prefetch tile 0 staging (summary K2/V2t)
    bf16x8 ka0, ka1, va0, va1;
    {
        const bf16_t* Kt = K2b + (size_t)bh * (SLEN * HD);
        const bf16_t* Vt = V2tb + (size_t)bh * (HD * SLEN);
        const bf16x8* ks = (const bf16x8*)(Kt + (size_t)srow * HD + scol);
        ka0 = ks[0]; ka1 = ks[1];
        const bf16x8* vs = (const bf16x8*)(Vt + (size_t)srow * SLEN + scol);
        va0 = vs[0]; va1 = vs[1];
    }
    int crel[4][4];   // rel ints for current tile (valid when tile>=1)

    for (int tile = 0; tile < 33; tile++) {
        // write prefetched staging
        *(bf16x8*)(Ks + srow * LDK + scol)     = ka0;
        *(bf16x8*)(Ks + srow * LDK + scol + 8) = ka1;
        *(bf16x8*)(Vs + srow * LDK + scol)     = va0;
        *(bf16x8*)(Vs + srow * LDK + scol + 8) = va1;
        __syncthreads();

        // prefetch next tile's staging (reg tiles, kk0_next = tile*64)
        if (tile < 32) {
            const bf16_t* Kt = Kb + ((size_t)bh * RLEN + tile * 64) * HD;
            const bf16_t* Vt = Vtb + (size_t)bh * HD * RLEN + tile * 64;
            const bf16x8* ks = (const bf16x8*)(Kt + (size_t)srow * HD + scol);
            ka0 = ks[0]; ka1 = ks[1];
            const bf16x8* vs = (const bf16x8*)(Vt + (size_t)srow * RLEN + scol);
            va0 = vs[0]; va1 = vs[1];
        }
        // prefetch next tile's rel_idx
        int nrel[4][4];
        if (tile < 32) {
            const int* rr = relbase + tile * 64;
#pragma unroll
            for (int reg = 0; reg < 4; reg++)
#pragma unroll
                for (int nt = 0; nt < 4; nt++)
                    nrel[reg][nt] = rr[(size_t)reg * RLEN + 16 * nt];
        }

        // S = Q K^T
        f32x4 S[4];
#pragma unroll
        for (int nt = 0; nt < 4; nt++) {
            f32x4 acc = {0.f, 0.f, 0.f, 0.f};
            bf16x8 kf0 = *(const bf16x8*)(Ks + (l15 + 16 * nt) * LDK + quad * 8);
            bf16x8 kf1 = *(const bf16x8*)(Ks + (l15 + 16 * nt) * LDK + 32 + quad * 8);
            acc = mfma16(qf0, kf0, acc);
            acc = mfma16(qf1, kf1, acc);
            S[nt] = acc;
        }

        // rel bias (current tile, rel ints already in registers)
        if (tile > 0) {
#pragma unroll
            for (int reg = 0; reg < 4; reg++) {
                int qlocal = wave * 16 + quad * 4 + reg;
#pragma unroll
                for (int nt = 0; nt < 4; nt++)
                    S[nt][reg] += (float)qrs[qlocal * 64 + crel[reg][nt]];
            }
        }

        // online softmax
        float tmax[4];
#pragma unroll
        for (int reg = 0; reg < 4; reg++) {
            float v = fmaxf(fmaxf(S[0][reg], S[1][reg]), fmaxf(S[2][reg], S[3][reg]));
#pragma unroll
            for (int o = 8; o > 0; o >>= 1) v = fmaxf(v, __shfl_xor(v, o));
            tmax[reg] = v;
        }
        float alpha[4], psum[4];
#pragma unroll
        for (int reg = 0; reg < 4; reg++) {
            float mn = fmaxf(m_i[reg], tmax[reg]);
            alpha[reg] = __expf(m_i[reg] - mn);
            m_i[reg] = mn;
            psum[reg] = 0.f;
        }
#pragma unroll
        for (int nt = 0; nt < 4; nt++)
#pragma unroll
            for (int reg = 0; reg < 4; reg++) {
                float p = __expf(S[nt][reg] - m_i[reg]);
                S[nt][reg] = p;
                psum[reg] += p;
            }
#pragma unroll
        for (int reg = 0; reg < 4; reg++) {
#pragma unroll
            for (int o = 8; o > 0; o >>= 1) psum[reg] += __shfl_xor(psum[reg], o);
            l_i[reg] = l_i[reg] * alpha[reg] + psum[reg];
        }
#pragma unroll
        for (int nt = 0; nt < 4; nt++) {
            O[nt][0] *= alpha[0]; O[nt][1] *= alpha[1];
            O[nt][2] *= alpha[2]; O[nt][3] *= alpha[3];
        }

        // P -> LDS (own wave strip), then PV
#pragma unroll
        for (int nt = 0; nt < 4; nt++)
#pragma unroll
            for (int reg = 0; reg < 4; reg++)
                Ps[(wave * 16 + quad * 4 + reg) * LDK + l15 + 16 * nt] = (bf16_t)S[nt][reg];

        bf16x8 pf0 = *(const bf16x8*)(Ps + (wave * 16 + l15) * LDK + quad * 8);
        bf16x8 pf1 = *(const bf16x8*)(Ps + (wave * 16 + l15) * LDK + 32 + quad * 8);
#pragma unroll
        for (int nt = 0; nt < 4; nt++) {
            bf16x8 vf0 = *(const bf16x8*)(Vs + (l15 + 16 * nt) * LDK + quad * 8);
            bf16x8 vf1 = *(const bf16x8*)(Vs + (l15 + 16 * nt) * LDK + 32 + quad * 8);
            O[nt] = mfma16(pf0, vf0, O[nt]);
            O[nt] = mfma16(pf1, vf1, O[nt]);
        }
        __syncthreads();

#pragma unroll
        for (int reg = 0; reg < 4; reg++)
#pragma unroll
            for (int nt = 0; nt < 4; nt++)
                crel[reg][nt] = nrel[reg][nt];
    }

    float linv[4];
#pragma unroll
    for (int reg = 0; reg < 4; reg++) linv[reg] = 1.0f / l_i[reg];
#pragma unroll
    for (int nt = 0; nt < 4; nt++)
#pragma unroll
        for (int reg = 0; reg < 4; reg++) {
            int q = q0 + wave * 16 + quad * 4 + reg;
            attn_out[((size_t)q * BSZ + b) * ED + h * HD + l15 + 16 * nt] =
                (bf16_t)(O[nt][reg] * linv[reg]);
        }
}

// ------------------------------------------------------------------
extern "C" void kernel_launch(void* const* d_in, const int* in_sizes, int n_in,
                              void* d_out, int out_size, void* d_ws, size_t ws_size,
                              hipStream_t stream)
{
    const float* reg_x    = (const float*)d_in[0];
    const int*   sum_ids  = (const int*)d_in[1];
    const int*   rel_idx  = (const int*)d_in[2];
    const float* emb_sum  = (const float*)d_in[5];
    const float* rel_emb0 = (const float*)d_in[6];
    const float* Wq = (const float*)d_in[7];
    const float* bq = (const float*)d_in[8];
    const float* Wk = (const float*)d_in[9];
    const float* bk = (const float*)d_in[10];
    const float* Wv = (const float*)d_in[11];
    const float* bv = (const float*)d_in[12];
    const float* Wr0 = (const float*)d_in[13];
    const float* br0 = (const float*)d_in[14];
    const float* Wk2 = (const float*)d_in[15];
    const float* bk2 = (const float*)d_in[16];
    const float* Wv2 = (const float*)d_in[17];
    const float* bv2 = (const float*)d_in[18];
    const float* Wo  = (const float*)d_in[19];
    const float* bo  = (const float*)d_in[20];
    const float* ln_k_g  = (const float*)d_in[21];
    const float* ln_k_b  = (const float*)d_in[22];
    const float* ln_v_g  = (const float*)d_in[23];
    const float* ln_v_b  = (const float*)d_in[24];
    const float* ln_k2_g = (const float*)d_in[25];
    const float* ln_k2_b = (const float*)d_in[26];
    const float* ln_v2_g = (const float*)d_in[27];
    const float* ln_v2_b = (const float*)d_in[28];

    const size_t QKV = (size_t)BSZ * NH * RLEN * HD;   // 4,194,304
    const size_t SUM = (size_t)BSZ * NH * SLEN * HD;   // 131,072

    float* ws  = (float*)d_ws;
    float* k   = ws;                    // fp32 K; later aliased by aob
    float* v   = k + QKV;               // fp32 V
    float* r0  = v + QKV;               // 65,536
    float* sx2 = r0 + (size_t)NH * NZ * HD;

    bf16_t* xb   = (bf16_t*)(sx2 + SUM);   // 4M bf16; dead after gemm_qkv -> aliased by po
    bf16_t* qb   = xb + QKV;
    bf16_t* kb   = qb + QKV;
    bf16_t* vtb  = kb + QKV;
    bf16_t* sqb  = vtb + QKV;
    bf16_t* k2b  = sqb + SUM;
    bf16_t* v2tb = k2b + SUM;
    bf16_t* wqt  = v2tb + SUM;          // wqt|wkt|wvt contiguous = [3072][1024]
    bf16_t* wkt  = wqt + (size_t)ED * ED;
    bf16_t* wvt  = wkt + (size_t)ED * ED;
    bf16_t* wot  = wvt + (size_t)ED * ED;
    bf16_t* wr0t = wot + (size_t)ED * ED;
    bf16_t* re0b = wr0t + (size_t)ED * NZ;
    bf16_t* aob  = (bf16_t*)k;          // alias: fp32 K dead after ln_heads
    float*  po   = (float*)xb;          // alias: xb dead after gemm_qkv
    float*  pm   = po + (size_t)BSZ * NH * NSPLIT * SLEN * HD;
    float*  pl   = pm + (size_t)BSZ * NH * NSPLIT * SLEN;

    const int M = RLEN * BSZ;   // 4096

    // --- conversions ---
    cvt_bf16<<<(int)(QKV / 1024), 256, 0, stream>>>(reg_x, xb, (int)QKV);
    cvt_bf16<<<4, 256, 0, stream>>>(rel_emb0, re0b, NZ * NZ);
    wt_batch<<<1040, 256, 0, stream>>>(Wq, Wk, Wv, Wo, Wr0, wqt, wkt, wvt, wot, wr0t);

    // --- fused QKV projection ---
    gemm_qkv<<<dim3(3 * ED / 128, M / 128), 256, 0, stream>>>(xb, wqt, bq, bk, bv, qb, k, v);

    ln_heads<<<(BSZ * NH * RLEN) / 4, 256, 0, stream>>>(k, ln_k_g, ln_k_b, kb, 1);
    lnv_t<<<dim3(RLEN / 64, BSZ * NH), 256, 0, stream>>>(v, ln_v_g, ln_v_b, vtb);

    // r0 = rel_emb0 @ Wr0 -> fp32 [h][z][d]
    gemm_mfma<<<dim3(ED / 128, 1), 256, 0, stream>>>(re0b, wr0t, br0, r0, NZ, NZ, ED, 1.f, 1, 0, 1, NZ);

    sumq_gather<<<SLEN * BSZ, 256, 0, stream>>>(emb_sum, sum_ids, sqb);

    sum_attn_split<<<dim3(BSZ * NH, NSPLIT), 256, 0, stream>>>(sqb, kb, vtb, r0, rel_idx, po, pm, pl);
    sum_reduce<<<dim3(BSZ * NH, 4), 256, 0, stream>>>(po, pm, pl, sx2);

    k2v2<<<BSZ * NH * SLEN, 64, 0, stream>>>(sx2, Wk2, bk2, Wv2, bv2,
                                             ln_k2_g, ln_k2_b, ln_v2_g, ln_v2_b, k2b, v2tb);

    reg_attn_mfma<<<BSZ * NH * (RLEN / 64), 256, 0, stream>>>(qb, kb, vtb, k2b, v2tb,
                                                              r0, rel_idx, aob);

    // final projection -> d_out fp32 (R,B,E)
    gemm_big<<<dim3(ED / 128, M / 128), 256, 0, stream>>>(aob, wot, bo, (float*)d_out, M, ED, ED);
}